// Round 1
// baseline (2349.200 us; speedup 1.0000x reference)
//
#include <hip/hip_runtime.h>
#include <math.h>

#define BB 32
#define LL 512
#define CHN 512
#define NHH 8
#define HDD 64

// ---------------------------------------------------------------------------
// Row LayerNorm over CH=512 (eps=1e-8, biased variance). 256 thr/row, in-place OK.
// ---------------------------------------------------------------------------
__global__ __launch_bounds__(256) void ln_kernel(
    const float* __restrict__ x, const float* __restrict__ g,
    const float* __restrict__ b, float* __restrict__ y)
{
    const int row = blockIdx.x;
    const int tid = threadIdx.x;
    const size_t base = (size_t)row * CHN;
    float2 v = *reinterpret_cast<const float2*>(x + base + tid * 2);
    float s  = v.x + v.y;
    float ss = v.x * v.x + v.y * v.y;
    #pragma unroll
    for (int m = 1; m < 64; m <<= 1) {
        s  += __shfl_xor(s, m);
        ss += __shfl_xor(ss, m);
    }
    __shared__ float red[8];
    const int wave = tid >> 6;
    if ((tid & 63) == 0) { red[wave] = s; red[4 + wave] = ss; }
    __syncthreads();
    s  = red[0] + red[1] + red[2] + red[3];
    ss = red[4] + red[5] + red[6] + red[7];
    const float mean = s * (1.0f / CHN);
    const float var  = ss * (1.0f / CHN) - mean * mean;
    const float inv  = rsqrtf(var + 1e-8f);
    const int c = tid * 2;
    float2 o;
    o.x = (v.x - mean) * inv * g[c]     + b[c];
    o.y = (v.y - mean) * inv * g[c + 1] + b[c + 1];
    *reinterpret_cast<float2*>(y + base + c) = o;
}

// ---------------------------------------------------------------------------
// Generic f32 GEMM: C[M,N] = act(A[M,K] @ W[N,K]^T + bias + pos[row%512]) + res
// 64x64 tile, BK=16, 256 threads, 4x4 per thread.
// act: 0=none 1=relu 2=swish. pos/bias/res nullable. res may alias C.
// ---------------------------------------------------------------------------
__global__ __launch_bounds__(256) void gemm_kernel(
    const float* __restrict__ A, int M, int K,
    const float* __restrict__ W, int ldw,
    const float* __restrict__ bias,
    const float* __restrict__ res,
    const float* __restrict__ pos,
    float* __restrict__ C, int N, int act)
{
    __shared__ float As[16][68];  // As[k][m]
    __shared__ float Ws[16][68];  // Ws[k][n]
    const int bm = blockIdx.y * 64;
    const int bn = blockIdx.x * 64;
    const int tid = threadIdx.x;
    const int tx = tid & 15, ty = tid >> 4;
    const int lr = tid >> 2;          // 0..63
    const int lk = (tid & 3) << 2;    // 0,4,8,12
    float acc[4][4] = {};

    for (int k0 = 0; k0 < K; k0 += 16) {
        float4 av = make_float4(0.f, 0.f, 0.f, 0.f);
        if (bm + lr < M)
            av = *reinterpret_cast<const float4*>(A + (size_t)(bm + lr) * K + k0 + lk);
        const float4 wv = *reinterpret_cast<const float4*>(W + (size_t)(bn + lr) * ldw + k0 + lk);
        __syncthreads();
        As[lk + 0][lr] = av.x; As[lk + 1][lr] = av.y; As[lk + 2][lr] = av.z; As[lk + 3][lr] = av.w;
        Ws[lk + 0][lr] = wv.x; Ws[lk + 1][lr] = wv.y; Ws[lk + 2][lr] = wv.z; Ws[lk + 3][lr] = wv.w;
        __syncthreads();
        #pragma unroll
        for (int kk = 0; kk < 16; ++kk) {
            const float4 a4 = *reinterpret_cast<const float4*>(&As[kk][ty * 4]);
            const float4 b4 = *reinterpret_cast<const float4*>(&Ws[kk][tx * 4]);
            const float ar[4] = {a4.x, a4.y, a4.z, a4.w};
            const float br[4] = {b4.x, b4.y, b4.z, b4.w};
            #pragma unroll
            for (int i = 0; i < 4; ++i)
                #pragma unroll
                for (int j = 0; j < 4; ++j)
                    acc[i][j] = fmaf(ar[i], br[j], acc[i][j]);
        }
    }

    #pragma unroll
    for (int i = 0; i < 4; ++i) {
        const int row = bm + ty * 4 + i;
        if (row >= M) break;
        #pragma unroll
        for (int j = 0; j < 4; ++j) {
            const int col = bn + tx * 4 + j;
            float v = acc[i][j];
            if (bias) v += bias[col];
            if (pos)  v += pos[(size_t)(row & (LL - 1)) * N + col];
            if (act == 1) v = fmaxf(v, 0.f);
            else if (act == 2) v = v / (1.f + __expf(-v));
            if (res) v += res[(size_t)row * N + col];
            C[(size_t)row * N + col] = v;
        }
    }
}

// ---------------------------------------------------------------------------
// Causal flash attention per (qtile, head, batch). Q,K,V: [B*L, CH], head h at
// cols h*64..h*64+63. K already has posK folded, V has posV folded.
// Writes Sout = Qin + softmax(QK^T/8)V.
// ---------------------------------------------------------------------------
__global__ __launch_bounds__(256) void attn_kernel(
    const float* __restrict__ Q, const float* __restrict__ K,
    const float* __restrict__ V, const float* __restrict__ Qin,
    float* __restrict__ Sout)
{
    const int qt = blockIdx.x;   // 0..7
    const int h  = blockIdx.y;   // 0..7
    const int b  = blockIdx.z;   // 0..31
    const int tid = threadIdx.x;
    const int tx = tid & 15, ty = tid >> 4;
    const int r0 = ty * 4, c0 = tx * 4;

    __shared__ float qT[64][68];  // qT[d][r]
    __shared__ float kv[64][68];  // K chunk: kv[d][m]; V chunk: kv[m][d]
    __shared__ float pl[64][68];  // p[r][m_local]

    const size_t rowbase = (size_t)b * LL + (size_t)qt * 64;
    const int hc = h * HDD;

    // stage Q tile (transposed)
    #pragma unroll
    for (int t = 0; t < 4; ++t) {
        const int c4 = tid + t * 256;
        const int r = c4 >> 4;
        const int d = (c4 & 15) << 2;
        const float4 qv = *reinterpret_cast<const float4*>(Q + (rowbase + r) * CHN + hc + d);
        qT[d + 0][r] = qv.x; qT[d + 1][r] = qv.y; qT[d + 2][r] = qv.z; qT[d + 3][r] = qv.w;
    }

    float acc[4][4] = {};
    float mrow[4], lrow[4];
    #pragma unroll
    for (int i = 0; i < 4; ++i) { mrow[i] = -1e30f; lrow[i] = 0.f; }

    for (int ch = 0; ch <= qt; ++ch) {
        const size_t mbase = (size_t)b * LL + (size_t)ch * 64;
        __syncthreads();  // prev PV reads of kv/pl done; qT staged (1st iter)
        #pragma unroll
        for (int t = 0; t < 4; ++t) {
            const int c4 = tid + t * 256;
            const int m = c4 >> 4;
            const int d = (c4 & 15) << 2;
            const float4 kx = *reinterpret_cast<const float4*>(K + (mbase + m) * CHN + hc + d);
            kv[d + 0][m] = kx.x; kv[d + 1][m] = kx.y; kv[d + 2][m] = kx.z; kv[d + 3][m] = kx.w;
        }
        __syncthreads();

        // S(4x4) = q @ K^T
        float s[4][4] = {};
        for (int d = 0; d < 64; ++d) {
            const float4 qa = *reinterpret_cast<const float4*>(&qT[d][r0]);
            const float4 kb = *reinterpret_cast<const float4*>(&kv[d][c0]);
            const float qr[4] = {qa.x, qa.y, qa.z, qa.w};
            const float kr[4] = {kb.x, kb.y, kb.z, kb.w};
            #pragma unroll
            for (int i = 0; i < 4; ++i)
                #pragma unroll
                for (int j = 0; j < 4; ++j)
                    s[i][j] = fmaf(qr[i], kr[j], s[i][j]);
        }
        const bool diag = (ch == qt);
        #pragma unroll
        for (int i = 0; i < 4; ++i)
            #pragma unroll
            for (int j = 0; j < 4; ++j) {
                float v = s[i][j] * 0.125f;
                if (diag && (c0 + j > r0 + i)) v = -1e30f;
                s[i][j] = v;
            }

        // online softmax update (row stats replicated across the 16 tx lanes)
        #pragma unroll
        for (int i = 0; i < 4; ++i) {
            float cm = fmaxf(fmaxf(s[i][0], s[i][1]), fmaxf(s[i][2], s[i][3]));
            cm = fmaxf(cm, __shfl_xor(cm, 1));
            cm = fmaxf(cm, __shfl_xor(cm, 2));
            cm = fmaxf(cm, __shfl_xor(cm, 4));
            cm = fmaxf(cm, __shfl_xor(cm, 8));
            const float mn = fmaxf(mrow[i], cm);
            const float f = __expf(mrow[i] - mn);
            float ps = 0.f;
            #pragma unroll
            for (int j = 0; j < 4; ++j) { s[i][j] = __expf(s[i][j] - mn); ps += s[i][j]; }
            ps += __shfl_xor(ps, 1);
            ps += __shfl_xor(ps, 2);
            ps += __shfl_xor(ps, 4);
            ps += __shfl_xor(ps, 8);
            lrow[i] = lrow[i] * f + ps;
            mrow[i] = mn;
            #pragma unroll
            for (int j = 0; j < 4; ++j) acc[i][j] *= f;
        }

        __syncthreads();  // all S reads of kv (K) done before V overwrite
        #pragma unroll
        for (int i = 0; i < 4; ++i)
            #pragma unroll
            for (int j = 0; j < 4; ++j)
                pl[r0 + i][c0 + j] = s[i][j];
        #pragma unroll
        for (int t = 0; t < 4; ++t) {
            const int c4 = tid + t * 256;
            const int m = c4 >> 4;
            const int d = (c4 & 15) << 2;
            const float4 vx = *reinterpret_cast<const float4*>(V + (mbase + m) * CHN + hc + d);
            *reinterpret_cast<float4*>(&kv[m][d]) = vx;
        }
        __syncthreads();

        // PV: acc[i][j] += sum_m p[r0+i][m] * V[m][c0+j]
        for (int m = 0; m < 64; ++m) {
            const float4 vv = *reinterpret_cast<const float4*>(&kv[m][c0]);
            const float vr[4] = {vv.x, vv.y, vv.z, vv.w};
            #pragma unroll
            for (int i = 0; i < 4; ++i) {
                const float p = pl[r0 + i][m];
                #pragma unroll
                for (int j = 0; j < 4; ++j)
                    acc[i][j] = fmaf(p, vr[j], acc[i][j]);
            }
        }
    }

    // epilogue: O/l + Qin residual
    #pragma unroll
    for (int i = 0; i < 4; ++i) {
        const float inv = 1.f / lrow[i];
        const size_t row = rowbase + r0 + i;
        const float4 qi = *reinterpret_cast<const float4*>(Qin + row * CHN + hc + c0);
        float4 o;
        o.x = acc[i][0] * inv + qi.x;
        o.y = acc[i][1] * inv + qi.y;
        o.z = acc[i][2] * inv + qi.z;
        o.w = acc[i][3] * inv + qi.w;
        *reinterpret_cast<float4*>(Sout + row * CHN + hc + c0) = o;
    }
}

// ---------------------------------------------------------------------------
// Diffusion timestep embedding: T0[b, j] = j<256 ? sin(t_b*f_j) : cos(t_b*f_{j-256})
// ---------------------------------------------------------------------------
__global__ __launch_bounds__(256) void temb_embed_kernel(
    const int* __restrict__ t, float* __restrict__ T0)
{
    const int idx = blockIdx.x * 256 + threadIdx.x;  // B*512
    const int b = idx >> 9, j = idx & 511;
    const float tv = (float)t[b];
    const int jj = (j < 256) ? j : j - 256;
    const float freq = __expf((float)jj * (-9.210340371976184f / 255.f));
    const float ang = tv * freq;
    T0[idx] = (j < 256) ? sinf(ang) : cosf(ang);
}

// x_t = seqs_nxt + temb[b] (broadcast over L)
__global__ __launch_bounds__(256) void add_temb_kernel(
    const float* __restrict__ xin, const float* __restrict__ temb,
    float* __restrict__ out)
{
    const size_t i4 = (size_t)blockIdx.x * 256 + threadIdx.x;
    const size_t elem = i4 * 4;
    const int b = (int)(elem >> 18);     // / (L*CH)
    const int c = (int)(elem & (CHN - 1));
    const float4 a = reinterpret_cast<const float4*>(xin)[i4];
    const float4 tv = *reinterpret_cast<const float4*>(temb + (size_t)b * CHN + c);
    float4 o;
    o.x = a.x + tv.x; o.y = a.y + tv.y; o.z = a.z + tv.z; o.w = a.w + tv.w;
    reinterpret_cast<float4*>(out)[i4] = o;
}

// ---------------------------------------------------------------------------
extern "C" void kernel_launch(void* const* d_in, const int* in_sizes, int n_in,
                              void* d_out, int out_size, void* d_ws, size_t ws_size,
                              hipStream_t stream)
{
    (void)in_sizes; (void)n_in; (void)out_size; (void)ws_size;
    const float* log_seqs = (const float*)d_in[0];
    const float* seqs_nxt = (const float*)d_in[1];
    const int*   tt       = (const int*)d_in[2];
    const float* qw  = (const float*)d_in[3];
    const float* qb  = (const float*)d_in[4];
    const float* kw  = (const float*)d_in[5];
    const float* kb  = (const float*)d_in[6];
    const float* vw  = (const float*)d_in[7];
    const float* vb  = (const float*)d_in[8];
    const float* ln1g = (const float*)d_in[9];
    const float* ln1b = (const float*)d_in[10];
    const float* ln2g = (const float*)d_in[11];
    const float* ln2b = (const float*)d_in[12];
    const float* c1w = (const float*)d_in[13];
    const float* c1b = (const float*)d_in[14];
    const float* c2w = (const float*)d_in[15];
    const float* c2b = (const float*)d_in[16];
    const float* posK = (const float*)d_in[17];
    const float* posV = (const float*)d_in[18];
    const float* lng = (const float*)d_in[19];
    const float* lnb = (const float*)d_in[20];
    const float* tw0 = (const float*)d_in[21];
    const float* tb0 = (const float*)d_in[22];
    const float* tw1 = (const float*)d_in[23];
    const float* tb1 = (const float*)d_in[24];
    const float* tw2 = (const float*)d_in[25];
    const float* tb2 = (const float*)d_in[26];
    const float* decw = (const float*)d_in[27];
    const float* decb = (const float*)d_in[28];

    const size_t SZ = (size_t)BB * LL * CHN;  // 8388608
    float* out = (float*)d_out;
    float* log_feats = out;
    float* dec = out + SZ;

    float* ws  = (float*)d_ws;
    float* S   = ws;            // running seqs
    float* QIN = ws + SZ;       // LN1 output
    float* KB  = ws + 2 * SZ;   // K' / later x_t
    float* T0  = ws + 3 * SZ;
    float* T1  = T0 + 32 * CHN;
    float* T2  = T1 + 32 * 2048;
    float* T3  = T2 + 32 * 2048;
    float* QB  = dec;           // Q / FFN hidden — free until decoder GEMMs
    float* VB  = log_feats;     // V' — free until final LN

    const int M = BB * LL;  // 16384

    auto gemm = [&](const float* A, int Mm, int K, const float* W, int ldw,
                    const float* bias, const float* res, const float* pos,
                    float* C, int N, int act) {
        dim3 grid(N / 64, (Mm + 63) / 64);
        gemm_kernel<<<grid, 256, 0, stream>>>(A, Mm, K, W, ldw, bias, res, pos, C, N, act);
    };

    const float* cur = log_seqs;
    for (int i = 0; i < 2; ++i) {
        const size_t wo = (size_t)i * CHN * CHN;
        const size_t bo = (size_t)i * CHN;
        ln_kernel<<<M, 256, 0, stream>>>(cur, ln1g + bo, ln1b + bo, QIN);
        gemm(QIN, M, CHN, qw + wo, CHN, qb + bo, nullptr, nullptr, QB, CHN, 0);
        gemm(cur, M, CHN, kw + wo, CHN, kb + bo, nullptr, posK, KB, CHN, 0);
        gemm(cur, M, CHN, vw + wo, CHN, vb + bo, nullptr, posV, VB, CHN, 0);
        attn_kernel<<<dim3(LL / 64, NHH, BB), 256, 0, stream>>>(QB, KB, VB, QIN, S);
        ln_kernel<<<M, 256, 0, stream>>>(S, ln2g + bo, ln2b + bo, S);
        gemm(S, M, CHN, c1w + wo, CHN, c1b + bo, nullptr, nullptr, QB, CHN, 1);
        gemm(QB, M, CHN, c2w + wo, CHN, c2b + bo, S, nullptr, S, CHN, 0);
        cur = S;
    }

    ln_kernel<<<M, 256, 0, stream>>>(S, lng, lnb, log_feats);

    temb_embed_kernel<<<(BB * CHN) / 256, 256, 0, stream>>>(tt, T0);
    gemm(T0, BB, CHN, tw0, CHN, tb0, nullptr, nullptr, T1, 2048, 2);
    gemm(T1, BB, 2048, tw1, 2048, tb1, nullptr, nullptr, T2, 2048, 2);
    gemm(T2, BB, 2048, tw2, 2048, tb2, nullptr, nullptr, T3, CHN, 0);
    add_temb_kernel<<<(M * CHN / 4) / 256, 256, 0, stream>>>(seqs_nxt, T3, KB);

    gemm(log_feats, M, CHN, decw, 2 * CHN, decb, nullptr, nullptr, dec, CHN, 0);
    gemm(KB, M, CHN, decw + CHN, 2 * CHN, nullptr, dec, nullptr, dec, CHN, 0);
}

// Round 2
// 1277.094 us; speedup vs baseline: 1.8395x; 1.8395x over previous
//
#include <hip/hip_runtime.h>
#include <math.h>

#define BB 32
#define LL 512
#define CHN 512
#define NHH 8
#define HDD 64

typedef __attribute__((ext_vector_type(8))) short short8;
typedef __attribute__((ext_vector_type(4))) float f32x4;

__device__ __forceinline__ float b2f(unsigned short s) {
    union { unsigned int u; float f; } c; c.u = ((unsigned int)s) << 16; return c.f;
}
__device__ __forceinline__ unsigned short f2b(float f) {
    union { float f; unsigned int u; } c; c.f = f;
    return (unsigned short)((c.u + 0x7fffu + ((c.u >> 16) & 1u)) >> 16);
}

// ---------------------------------------------------------------------------
// f32 -> bf16 bulk convert (4 elems/thread)
// ---------------------------------------------------------------------------
__global__ __launch_bounds__(256) void cvt_kernel(
    const float* __restrict__ x, unsigned short* __restrict__ y, int n4)
{
    int i = blockIdx.x * 256 + threadIdx.x;
    if (i >= n4) return;
    const float4 v = reinterpret_cast<const float4*>(x)[i];
    ushort4 o;
    o.x = f2b(v.x); o.y = f2b(v.y); o.z = f2b(v.z); o.w = f2b(v.w);
    reinterpret_cast<ushort4*>(y)[i] = o;
}

// ---------------------------------------------------------------------------
// Row LayerNorm over CH=512 (eps=1e-8). Optional f32 and/or bf16 outputs.
// ---------------------------------------------------------------------------
__global__ __launch_bounds__(256) void ln_kernel(
    const float* __restrict__ x, const float* __restrict__ g,
    const float* __restrict__ b, float* __restrict__ yf,
    unsigned short* __restrict__ yb)
{
    const int row = blockIdx.x;
    const int tid = threadIdx.x;
    const size_t base = (size_t)row * CHN;
    float2 v = *reinterpret_cast<const float2*>(x + base + tid * 2);
    float s  = v.x + v.y;
    float ss = v.x * v.x + v.y * v.y;
    #pragma unroll
    for (int m = 1; m < 64; m <<= 1) {
        s  += __shfl_xor(s, m);
        ss += __shfl_xor(ss, m);
    }
    __shared__ float red[8];
    const int wave = tid >> 6;
    if ((tid & 63) == 0) { red[wave] = s; red[4 + wave] = ss; }
    __syncthreads();
    s  = red[0] + red[1] + red[2] + red[3];
    ss = red[4] + red[5] + red[6] + red[7];
    const float mean = s * (1.0f / CHN);
    const float var  = ss * (1.0f / CHN) - mean * mean;
    const float inv  = rsqrtf(var + 1e-8f);
    const int c = tid * 2;
    float2 o;
    o.x = (v.x - mean) * inv * g[c]     + b[c];
    o.y = (v.y - mean) * inv * g[c + 1] + b[c + 1];
    if (yf) *reinterpret_cast<float2*>(yf + base + c) = o;
    if (yb) {
        ushort2 ob; ob.x = f2b(o.x); ob.y = f2b(o.y);
        *reinterpret_cast<ushort2*>(yb + base + c) = ob;
    }
}

// ---------------------------------------------------------------------------
// bf16 MFMA GEMM: C[16384,512] = act(A[16384,512] @ W[512,ldw](rows=N cols=K)^T
//                                    + bias + pos[row%512]) + res
// 128x128 tile, BK=32, 256 thr / 4 waves, 16x16x32 bf16 MFMA,
// global_load_lds(16B) staging, XCD-swizzled 1-D grid of 512 blocks.
// LDS chunk layout: chunk c = hi*128 + r  (hi = k-octet 0..3, r = tile row),
// 16B per chunk = 8 bf16 = one MFMA operand slice.
// ---------------------------------------------------------------------------
__device__ __forceinline__ void gl16(const unsigned short* g, unsigned short* l) {
    __builtin_amdgcn_global_load_lds(
        (const __attribute__((address_space(1))) unsigned int*)g,
        (__attribute__((address_space(3))) unsigned int*)l, 16, 0, 0);
}

__global__ __launch_bounds__(256) void mgemm_kernel(
    const unsigned short* __restrict__ A,
    const unsigned short* __restrict__ W, int ldw,
    const float* __restrict__ bias,
    const float* __restrict__ pos,
    const float* __restrict__ res,
    float* __restrict__ outf,
    unsigned short* __restrict__ outb,
    int act)
{
    __shared__ alignas(16) unsigned short lA[4096];  // 512 chunks x 16B
    __shared__ alignas(16) unsigned short lB[4096];

    const int tid  = threadIdx.x;
    const int lane = tid & 63;
    const int wid  = tid >> 6;

    // XCD-aware swizzle: 512 blocks, 8 XCDs, 64-contiguous per XCD
    const int bid = blockIdx.x;
    const int swz = (bid & 7) * 64 + (bid >> 3);
    const int by = swz >> 2, bx = swz & 3;
    const int bm = by * 128, bn = bx * 128;

    // staging sources: wave wid covers k-octet hi=wid; j=0/1 covers rows 0-63/64-127
    const unsigned short* aS0 = A + (size_t)(bm + lane) * 512 + wid * 8;
    const unsigned short* aS1 = A + (size_t)(bm + 64 + lane) * 512 + wid * 8;
    const unsigned short* wS0 = W + (size_t)(bn + lane) * ldw + wid * 8;
    const unsigned short* wS1 = W + (size_t)(bn + 64 + lane) * ldw + wid * 8;
    unsigned short* lA0 = lA + (wid * 128) * 8;
    unsigned short* lA1 = lA + (wid * 128 + 64) * 8;
    unsigned short* lB0 = lB + (wid * 128) * 8;
    unsigned short* lB1 = lB + (wid * 128 + 64) * 8;

    const int wr = wid >> 1, wc = wid & 1;      // wave tile (64x64)
    const int fr = lane & 15;                   // row/col within 16
    const int fq = lane >> 4;                   // k-octet / row-quad

    f32x4 acc[4][4];
    #pragma unroll
    for (int m = 0; m < 4; ++m)
        #pragma unroll
        for (int n = 0; n < 4; ++n)
            acc[m][n] = (f32x4){0.f, 0.f, 0.f, 0.f};

    const unsigned short* pa = lA + (fq * 128 + wr * 64 + fr) * 8;
    const unsigned short* pb = lB + (fq * 128 + wc * 64 + fr) * 8;

    for (int k0 = 0; k0 < 512; k0 += 32) {
        __syncthreads();
        gl16(aS0 + k0, lA0);
        gl16(aS1 + k0, lA1);
        gl16(wS0 + k0, lB0);
        gl16(wS1 + k0, lB1);
        __syncthreads();

        short8 aF[4], bF[4];
        #pragma unroll
        for (int m = 0; m < 4; ++m)
            aF[m] = *reinterpret_cast<const short8*>(pa + m * 128);
        #pragma unroll
        for (int n = 0; n < 4; ++n)
            bF[n] = *reinterpret_cast<const short8*>(pb + n * 128);
        #pragma unroll
        for (int m = 0; m < 4; ++m)
            #pragma unroll
            for (int n = 0; n < 4; ++n)
                acc[m][n] = __builtin_amdgcn_mfma_f32_16x16x32_bf16(
                    aF[m], bF[n], acc[m][n], 0, 0, 0);
    }

    // epilogue: C[row][col], col = .. + fr, row = .. + fq*4 + reg
    const int row0 = bm + wr * 64, col0 = bn + wc * 64;
    #pragma unroll
    for (int m = 0; m < 4; ++m) {
        #pragma unroll
        for (int n = 0; n < 4; ++n) {
            const int col = col0 + n * 16 + fr;
            const float bia = bias ? bias[col] : 0.f;
            #pragma unroll
            for (int r = 0; r < 4; ++r) {
                const int row = row0 + m * 16 + fq * 4 + r;
                float v = acc[m][n][r] + bia;
                if (pos) v += pos[(size_t)(row & (LL - 1)) * CHN + col];
                if (act == 1) v = fmaxf(v, 0.f);
                const size_t idx = (size_t)row * CHN + col;
                if (res) v += res[idx];
                if (outf) outf[idx] = v;
                if (outb) outb[idx] = f2b(v);
            }
        }
    }
}

// ---------------------------------------------------------------------------
// f32 GEMM for the tiny temb path (M=32). Unchanged from round 1.
// ---------------------------------------------------------------------------
__global__ __launch_bounds__(256) void gemm_kernel(
    const float* __restrict__ A, int M, int K,
    const float* __restrict__ W, int ldw,
    const float* __restrict__ bias,
    const float* __restrict__ res,
    const float* __restrict__ pos,
    float* __restrict__ C, int N, int act)
{
    __shared__ float As[16][68];
    __shared__ float Ws[16][68];
    const int bm = blockIdx.y * 64;
    const int bn = blockIdx.x * 64;
    const int tid = threadIdx.x;
    const int tx = tid & 15, ty = tid >> 4;
    const int lr = tid >> 2;
    const int lk = (tid & 3) << 2;
    float acc[4][4] = {};

    for (int k0 = 0; k0 < K; k0 += 16) {
        float4 av = make_float4(0.f, 0.f, 0.f, 0.f);
        if (bm + lr < M)
            av = *reinterpret_cast<const float4*>(A + (size_t)(bm + lr) * K + k0 + lk);
        const float4 wv = *reinterpret_cast<const float4*>(W + (size_t)(bn + lr) * ldw + k0 + lk);
        __syncthreads();
        As[lk + 0][lr] = av.x; As[lk + 1][lr] = av.y; As[lk + 2][lr] = av.z; As[lk + 3][lr] = av.w;
        Ws[lk + 0][lr] = wv.x; Ws[lk + 1][lr] = wv.y; Ws[lk + 2][lr] = wv.z; Ws[lk + 3][lr] = wv.w;
        __syncthreads();
        #pragma unroll
        for (int kk = 0; kk < 16; ++kk) {
            const float4 a4 = *reinterpret_cast<const float4*>(&As[kk][ty * 4]);
            const float4 b4 = *reinterpret_cast<const float4*>(&Ws[kk][tx * 4]);
            const float ar[4] = {a4.x, a4.y, a4.z, a4.w};
            const float br[4] = {b4.x, b4.y, b4.z, b4.w};
            #pragma unroll
            for (int i = 0; i < 4; ++i)
                #pragma unroll
                for (int j = 0; j < 4; ++j)
                    acc[i][j] = fmaf(ar[i], br[j], acc[i][j]);
        }
    }

    #pragma unroll
    for (int i = 0; i < 4; ++i) {
        const int row = bm + ty * 4 + i;
        if (row >= M) break;
        #pragma unroll
        for (int j = 0; j < 4; ++j) {
            const int col = bn + tx * 4 + j;
            float v = acc[i][j];
            if (bias) v += bias[col];
            if (pos)  v += pos[(size_t)(row & (LL - 1)) * N + col];
            if (act == 1) v = fmaxf(v, 0.f);
            else if (act == 2) v = v / (1.f + __expf(-v));
            if (res) v += res[(size_t)row * N + col];
            C[(size_t)row * N + col] = v;
        }
    }
}

// ---------------------------------------------------------------------------
// Causal flash attention. Q,V f32; K' bf16; Qin residual bf16. Sout f32.
// ---------------------------------------------------------------------------
__global__ __launch_bounds__(256) void attn_kernel(
    const float* __restrict__ Q, const unsigned short* __restrict__ K,
    const float* __restrict__ V, const unsigned short* __restrict__ Qin,
    float* __restrict__ Sout)
{
    const int qt = blockIdx.x;
    const int h  = blockIdx.y;
    const int b  = blockIdx.z;
    const int tid = threadIdx.x;
    const int tx = tid & 15, ty = tid >> 4;
    const int r0 = ty * 4, c0 = tx * 4;

    __shared__ float qT[64][68];
    __shared__ float kv[64][68];
    __shared__ float pl[64][68];

    const size_t rowbase = (size_t)b * LL + (size_t)qt * 64;
    const int hc = h * HDD;

    #pragma unroll
    for (int t = 0; t < 4; ++t) {
        const int c4 = tid + t * 256;
        const int r = c4 >> 4;
        const int d = (c4 & 15) << 2;
        const float4 qv = *reinterpret_cast<const float4*>(Q + (rowbase + r) * CHN + hc + d);
        qT[d + 0][r] = qv.x; qT[d + 1][r] = qv.y; qT[d + 2][r] = qv.z; qT[d + 3][r] = qv.w;
    }

    float acc[4][4] = {};
    float mrow[4], lrow[4];
    #pragma unroll
    for (int i = 0; i < 4; ++i) { mrow[i] = -1e30f; lrow[i] = 0.f; }

    for (int ch = 0; ch <= qt; ++ch) {
        const size_t mbase = (size_t)b * LL + (size_t)ch * 64;
        __syncthreads();
        #pragma unroll
        for (int t = 0; t < 4; ++t) {
            const int c4 = tid + t * 256;
            const int m = c4 >> 4;
            const int d = (c4 & 15) << 2;
            const ushort4 kx = *reinterpret_cast<const ushort4*>(K + (mbase + m) * CHN + hc + d);
            kv[d + 0][m] = b2f(kx.x); kv[d + 1][m] = b2f(kx.y);
            kv[d + 2][m] = b2f(kx.z); kv[d + 3][m] = b2f(kx.w);
        }
        __syncthreads();

        float s[4][4] = {};
        for (int d = 0; d < 64; ++d) {
            const float4 qa = *reinterpret_cast<const float4*>(&qT[d][r0]);
            const float4 kb = *reinterpret_cast<const float4*>(&kv[d][c0]);
            const float qr[4] = {qa.x, qa.y, qa.z, qa.w};
            const float kr[4] = {kb.x, kb.y, kb.z, kb.w};
            #pragma unroll
            for (int i = 0; i < 4; ++i)
                #pragma unroll
                for (int j = 0; j < 4; ++j)
                    s[i][j] = fmaf(qr[i], kr[j], s[i][j]);
        }
        const bool diag = (ch == qt);
        #pragma unroll
        for (int i = 0; i < 4; ++i)
            #pragma unroll
            for (int j = 0; j < 4; ++j) {
                float v = s[i][j] * 0.125f;
                if (diag && (c0 + j > r0 + i)) v = -1e30f;
                s[i][j] = v;
            }

        #pragma unroll
        for (int i = 0; i < 4; ++i) {
            float cm = fmaxf(fmaxf(s[i][0], s[i][1]), fmaxf(s[i][2], s[i][3]));
            cm = fmaxf(cm, __shfl_xor(cm, 1));
            cm = fmaxf(cm, __shfl_xor(cm, 2));
            cm = fmaxf(cm, __shfl_xor(cm, 4));
            cm = fmaxf(cm, __shfl_xor(cm, 8));
            const float mn = fmaxf(mrow[i], cm);
            const float f = __expf(mrow[i] - mn);
            float ps = 0.f;
            #pragma unroll
            for (int j = 0; j < 4; ++j) { s[i][j] = __expf(s[i][j] - mn); ps += s[i][j]; }
            ps += __shfl_xor(ps, 1);
            ps += __shfl_xor(ps, 2);
            ps += __shfl_xor(ps, 4);
            ps += __shfl_xor(ps, 8);
            lrow[i] = lrow[i] * f + ps;
            mrow[i] = mn;
            #pragma unroll
            for (int j = 0; j < 4; ++j) acc[i][j] *= f;
        }

        __syncthreads();
        #pragma unroll
        for (int i = 0; i < 4; ++i)
            #pragma unroll
            for (int j = 0; j < 4; ++j)
                pl[r0 + i][c0 + j] = s[i][j];
        #pragma unroll
        for (int t = 0; t < 4; ++t) {
            const int c4 = tid + t * 256;
            const int m = c4 >> 4;
            const int d = (c4 & 15) << 2;
            const float4 vx = *reinterpret_cast<const float4*>(V + (mbase + m) * CHN + hc + d);
            *reinterpret_cast<float4*>(&kv[m][d]) = vx;
        }
        __syncthreads();

        for (int m = 0; m < 64; ++m) {
            const float4 vv = *reinterpret_cast<const float4*>(&kv[m][c0]);
            const float vr[4] = {vv.x, vv.y, vv.z, vv.w};
            #pragma unroll
            for (int i = 0; i < 4; ++i) {
                const float p = pl[r0 + i][m];
                #pragma unroll
                for (int j = 0; j < 4; ++j)
                    acc[i][j] = fmaf(p, vr[j], acc[i][j]);
            }
        }
    }

    #pragma unroll
    for (int i = 0; i < 4; ++i) {
        const float inv = 1.f / lrow[i];
        const size_t row = rowbase + r0 + i;
        const ushort4 qi = *reinterpret_cast<const ushort4*>(Qin + row * CHN + hc + c0);
        float4 o;
        o.x = acc[i][0] * inv + b2f(qi.x);
        o.y = acc[i][1] * inv + b2f(qi.y);
        o.z = acc[i][2] * inv + b2f(qi.z);
        o.w = acc[i][3] * inv + b2f(qi.w);
        *reinterpret_cast<float4*>(Sout + row * CHN + hc + c0) = o;
    }
}

// ---------------------------------------------------------------------------
__global__ __launch_bounds__(256) void temb_embed_kernel(
    const int* __restrict__ t, float* __restrict__ T0)
{
    const int idx = blockIdx.x * 256 + threadIdx.x;
    const int b = idx >> 9, j = idx & 511;
    const float tv = (float)t[b];
    const int jj = (j < 256) ? j : j - 256;
    const float freq = __expf((float)jj * (-9.210340371976184f / 255.f));
    const float ang = tv * freq;
    T0[idx] = (j < 256) ? sinf(ang) : cosf(ang);
}

// x_t = seqs_nxt + temb[b]  ->  bf16
__global__ __launch_bounds__(256) void add_temb_kernel(
    const float* __restrict__ xin, const float* __restrict__ temb,
    unsigned short* __restrict__ out)
{
    const size_t i4 = (size_t)blockIdx.x * 256 + threadIdx.x;
    const size_t elem = i4 * 4;
    const int b = (int)(elem >> 18);
    const int c = (int)(elem & (CHN - 1));
    const float4 a = reinterpret_cast<const float4*>(xin)[i4];
    const float4 tv = *reinterpret_cast<const float4*>(temb + (size_t)b * CHN + c);
    ushort4 o;
    o.x = f2b(a.x + tv.x); o.y = f2b(a.y + tv.y);
    o.z = f2b(a.z + tv.z); o.w = f2b(a.w + tv.w);
    reinterpret_cast<ushort4*>(out)[i4] = o;
}

// ---------------------------------------------------------------------------
extern "C" void kernel_launch(void* const* d_in, const int* in_sizes, int n_in,
                              void* d_out, int out_size, void* d_ws, size_t ws_size,
                              hipStream_t stream)
{
    (void)in_sizes; (void)n_in; (void)out_size; (void)ws_size;
    const float* log_seqs = (const float*)d_in[0];
    const float* seqs_nxt = (const float*)d_in[1];
    const int*   tt       = (const int*)d_in[2];
    const float* qw  = (const float*)d_in[3];
    const float* qb  = (const float*)d_in[4];
    const float* kw  = (const float*)d_in[5];
    const float* kb  = (const float*)d_in[6];
    const float* vw  = (const float*)d_in[7];
    const float* vb  = (const float*)d_in[8];
    const float* ln1g = (const float*)d_in[9];
    const float* ln1b = (const float*)d_in[10];
    const float* ln2g = (const float*)d_in[11];
    const float* ln2b = (const float*)d_in[12];
    const float* c1w = (const float*)d_in[13];
    const float* c1b = (const float*)d_in[14];
    const float* c2w = (const float*)d_in[15];
    const float* c2b = (const float*)d_in[16];
    const float* posK = (const float*)d_in[17];
    const float* posV = (const float*)d_in[18];
    const float* lng = (const float*)d_in[19];
    const float* lnb = (const float*)d_in[20];
    const float* tw0 = (const float*)d_in[21];
    const float* tb0 = (const float*)d_in[22];
    const float* tw1 = (const float*)d_in[23];
    const float* tb1 = (const float*)d_in[24];
    const float* tw2 = (const float*)d_in[25];
    const float* tb2 = (const float*)d_in[26];
    const float* decw = (const float*)d_in[27];
    const float* decb = (const float*)d_in[28];

    const size_t SZ = (size_t)BB * LL * CHN;  // 8388608
    const int M = BB * LL;                    // 16384
    float* out = (float*)d_out;
    float* log_feats = out;
    float* dec = out + SZ;
    float* QB = dec;        // Q lives in dec half until decoder GEMMs
    float* VB = log_feats;  // V' lives in log_feats half until final LN

    float* ws = (float*)d_ws;
    float* S = ws;                                            // SZ f32
    unsigned short* KBb = (unsigned short*)(ws + SZ);         // SZ bf16
    unsigned short* R0  = (unsigned short*)(ws + SZ + SZ / 2);
    unsigned short* R1  = (unsigned short*)(ws + 2 * SZ);
    unsigned short* WBu = (unsigned short*)(ws + 2 * SZ + SZ / 2);  // 3145728 bf16
    float* T0 = ws + 2 * SZ + SZ / 2 + 1572864;
    float* T1 = T0 + 32 * CHN;
    float* T2 = T1 + 32 * 2048;
    float* T3 = T2 + 32 * 2048;

    const size_t WQ = 0, WK = 524288, WV = 1048576, WC1 = 1572864,
                 WC2 = 2097152, WDEC = 2621440;

    auto cvt = [&](const float* x, unsigned short* y, int n) {
        cvt_kernel<<<(n / 4 + 255) / 256, 256, 0, stream>>>(x, y, n / 4);
    };
    auto mg = [&](const unsigned short* A, const unsigned short* W, int ldw,
                  const float* bias, const float* pos, const float* res,
                  float* outf, unsigned short* outb, int act) {
        mgemm_kernel<<<512, 256, 0, stream>>>(A, W, ldw, bias, pos, res, outf, outb, act);
    };
    auto gemm = [&](const float* A, int Mm, int K, const float* W, int ldw,
                    const float* bias, const float* res, const float* pos,
                    float* C, int N, int act) {
        dim3 grid(N / 64, (Mm + 63) / 64);
        gemm_kernel<<<grid, 256, 0, stream>>>(A, Mm, K, W, ldw, bias, res, pos, C, N, act);
    };

    // weight + input conversions
    cvt(qw,  WBu + WQ,  524288);
    cvt(kw,  WBu + WK,  524288);
    cvt(vw,  WBu + WV,  524288);
    cvt(c1w, WBu + WC1, 524288);
    cvt(c2w, WBu + WC2, 524288);
    cvt(decw, WBu + WDEC, 524288);
    cvt(log_seqs, R1, (int)SZ);  // layer-0 curb

    const float* cur = log_seqs;
    for (int i = 0; i < 2; ++i) {
        const size_t wo = (size_t)i * 262144;
        const size_t bo = (size_t)i * CHN;
        unsigned short* qinb = (i == 0) ? R0 : R1;
        unsigned short* curb = (i == 0) ? R1 : R0;
        unsigned short* smb  = qinb;   // reuses qinb slot after attn
        unsigned short* hb   = curb;   // reuses curb slot after V-GEMM
        unsigned short* ncb  = (i == 0) ? qinb : nullptr;  // next layer's curb

        ln_kernel<<<M, 256, 0, stream>>>(cur, ln1g + bo, ln1b + bo, nullptr, qinb);
        mg(qinb, WBu + WQ + wo, 512, qb + bo, nullptr, nullptr, QB, nullptr, 0);
        mg(curb, WBu + WK + wo, 512, kb + bo, posK, nullptr, nullptr, KBb, 0);
        mg(curb, WBu + WV + wo, 512, vb + bo, posV, nullptr, VB, nullptr, 0);
        attn_kernel<<<dim3(LL / 64, NHH, BB), 256, 0, stream>>>(QB, KBb, VB, qinb, S);
        ln_kernel<<<M, 256, 0, stream>>>(S, ln2g + bo, ln2b + bo, S, smb);
        mg(smb, WBu + WC1 + wo, 512, c1b + bo, nullptr, nullptr, nullptr, hb, 1);
        mg(hb, WBu + WC2 + wo, 512, c2b + bo, nullptr, S, S, ncb, 0);
        cur = S;
    }

    ln_kernel<<<M, 256, 0, stream>>>(S, lng, lnb, log_feats, R0);

    temb_embed_kernel<<<(BB * CHN) / 256, 256, 0, stream>>>(tt, T0);
    gemm(T0, BB, CHN, tw0, CHN, tb0, nullptr, nullptr, T1, 2048, 2);
    gemm(T1, BB, 2048, tw1, 2048, tb1, nullptr, nullptr, T2, 2048, 2);
    gemm(T2, BB, 2048, tw2, 2048, tb2, nullptr, nullptr, T3, CHN, 0);
    add_temb_kernel<<<(M * CHN / 4) / 256, 256, 0, stream>>>(seqs_nxt, T3, R1);

    mg(R0, WBu + WDEC, 1024, decb, nullptr, nullptr, dec, nullptr, 0);
    mg(R1, WBu + WDEC + 512, 1024, nullptr, nullptr, dec, dec, nullptr, 0);
}

// Round 3
// 949.687 us; speedup vs baseline: 2.4737x; 1.3448x over previous
//
#include <hip/hip_runtime.h>
#include <math.h>

#define BB 32
#define LL 512
#define CHN 512
#define NHH 8
#define HDD 64

typedef __attribute__((ext_vector_type(8))) short short8;
typedef __attribute__((ext_vector_type(4))) float f32x4;

__device__ __forceinline__ float b2f(unsigned short s) {
    union { unsigned int u; float f; } c; c.u = ((unsigned int)s) << 16; return c.f;
}
__device__ __forceinline__ unsigned short f2b(float f) {
    union { float f; unsigned int u; } c; c.f = f;
    return (unsigned short)((c.u + 0x7fffu + ((c.u >> 16) & 1u)) >> 16);
}

// swizzled ushort index for a [rows][64] bf16 LDS tile (breaks 128B-stride conflicts)
#define SWZ(row, col) ((((row) * 64 + (col))) ^ (((row) & 7) << 3))

// ---------------------------------------------------------------------------
// f32 -> bf16 bulk convert
// ---------------------------------------------------------------------------
__global__ __launch_bounds__(256) void cvt_kernel(
    const float* __restrict__ x, unsigned short* __restrict__ y, int n4)
{
    int i = blockIdx.x * 256 + threadIdx.x;
    if (i >= n4) return;
    const float4 v = reinterpret_cast<const float4*>(x)[i];
    ushort4 o;
    o.x = f2b(v.x); o.y = f2b(v.y); o.z = f2b(v.z); o.w = f2b(v.w);
    reinterpret_cast<ushort4*>(y)[i] = o;
}

// ---------------------------------------------------------------------------
// Row LayerNorm over CH=512 (eps=1e-8). Optional f32 and/or bf16 outputs.
// ---------------------------------------------------------------------------
__global__ __launch_bounds__(256) void ln_kernel(
    const float* __restrict__ x, const float* __restrict__ g,
    const float* __restrict__ b, float* __restrict__ yf,
    unsigned short* __restrict__ yb)
{
    const int row = blockIdx.x;
    const int tid = threadIdx.x;
    const size_t base = (size_t)row * CHN;
    float2 v = *reinterpret_cast<const float2*>(x + base + tid * 2);
    float s  = v.x + v.y;
    float ss = v.x * v.x + v.y * v.y;
    #pragma unroll
    for (int m = 1; m < 64; m <<= 1) {
        s  += __shfl_xor(s, m);
        ss += __shfl_xor(ss, m);
    }
    __shared__ float red[8];
    const int wave = tid >> 6;
    if ((tid & 63) == 0) { red[wave] = s; red[4 + wave] = ss; }
    __syncthreads();
    s  = red[0] + red[1] + red[2] + red[3];
    ss = red[4] + red[5] + red[6] + red[7];
    const float mean = s * (1.0f / CHN);
    const float var  = ss * (1.0f / CHN) - mean * mean;
    const float inv  = rsqrtf(var + 1e-8f);
    const int c = tid * 2;
    float2 o;
    o.x = (v.x - mean) * inv * g[c]     + b[c];
    o.y = (v.y - mean) * inv * g[c + 1] + b[c + 1];
    if (yf) *reinterpret_cast<float2*>(yf + base + c) = o;
    if (yb) {
        ushort2 ob; ob.x = f2b(o.x); ob.y = f2b(o.y);
        *reinterpret_cast<ushort2*>(yb + base + c) = ob;
    }
}

// ---------------------------------------------------------------------------
// bf16 MFMA GEMM (unchanged from round 2): 128x128 tile, BK=32, 4 waves.
// ---------------------------------------------------------------------------
__device__ __forceinline__ void gl16(const unsigned short* g, unsigned short* l) {
    __builtin_amdgcn_global_load_lds(
        (const __attribute__((address_space(1))) unsigned int*)g,
        (__attribute__((address_space(3))) unsigned int*)l, 16, 0, 0);
}

__global__ __launch_bounds__(256) void mgemm_kernel(
    const unsigned short* __restrict__ A,
    const unsigned short* __restrict__ W, int ldw,
    const float* __restrict__ bias,
    const float* __restrict__ pos,
    const float* __restrict__ res,
    float* __restrict__ outf,
    unsigned short* __restrict__ outb,
    int act)
{
    __shared__ alignas(16) unsigned short lA[4096];
    __shared__ alignas(16) unsigned short lB[4096];

    const int tid  = threadIdx.x;
    const int lane = tid & 63;
    const int wid  = tid >> 6;

    const int bid = blockIdx.x;
    const int swz = (bid & 7) * 64 + (bid >> 3);
    const int by = swz >> 2, bx = swz & 3;
    const int bm = by * 128, bn = bx * 128;

    const unsigned short* aS0 = A + (size_t)(bm + lane) * 512 + wid * 8;
    const unsigned short* aS1 = A + (size_t)(bm + 64 + lane) * 512 + wid * 8;
    const unsigned short* wS0 = W + (size_t)(bn + lane) * ldw + wid * 8;
    const unsigned short* wS1 = W + (size_t)(bn + 64 + lane) * ldw + wid * 8;
    unsigned short* lA0 = lA + (wid * 128) * 8;
    unsigned short* lA1 = lA + (wid * 128 + 64) * 8;
    unsigned short* lB0 = lB + (wid * 128) * 8;
    unsigned short* lB1 = lB + (wid * 128 + 64) * 8;

    const int wr = wid >> 1, wc = wid & 1;
    const int fr = lane & 15;
    const int fq = lane >> 4;

    f32x4 acc[4][4];
    #pragma unroll
    for (int m = 0; m < 4; ++m)
        #pragma unroll
        for (int n = 0; n < 4; ++n)
            acc[m][n] = (f32x4){0.f, 0.f, 0.f, 0.f};

    const unsigned short* pa = lA + (fq * 128 + wr * 64 + fr) * 8;
    const unsigned short* pb = lB + (fq * 128 + wc * 64 + fr) * 8;

    for (int k0 = 0; k0 < 512; k0 += 32) {
        __syncthreads();
        gl16(aS0 + k0, lA0);
        gl16(aS1 + k0, lA1);
        gl16(wS0 + k0, lB0);
        gl16(wS1 + k0, lB1);
        __syncthreads();

        short8 aF[4], bF[4];
        #pragma unroll
        for (int m = 0; m < 4; ++m)
            aF[m] = *reinterpret_cast<const short8*>(pa + m * 128);
        #pragma unroll
        for (int n = 0; n < 4; ++n)
            bF[n] = *reinterpret_cast<const short8*>(pb + n * 128);
        #pragma unroll
        for (int m = 0; m < 4; ++m)
            #pragma unroll
            for (int n = 0; n < 4; ++n)
                acc[m][n] = __builtin_amdgcn_mfma_f32_16x16x32_bf16(
                    aF[m], bF[n], acc[m][n], 0, 0, 0);
    }

    const int row0 = bm + wr * 64, col0 = bn + wc * 64;
    #pragma unroll
    for (int m = 0; m < 4; ++m) {
        #pragma unroll
        for (int n = 0; n < 4; ++n) {
            const int col = col0 + n * 16 + fr;
            const float bia = bias ? bias[col] : 0.f;
            #pragma unroll
            for (int r = 0; r < 4; ++r) {
                const int row = row0 + m * 16 + fq * 4 + r;
                float v = acc[m][n][r] + bia;
                if (pos) v += pos[(size_t)(row & (LL - 1)) * CHN + col];
                if (act == 1) v = fmaxf(v, 0.f);
                const size_t idx = (size_t)row * CHN + col;
                if (res) v += res[idx];
                if (outf) outf[idx] = v;
                if (outb) outb[idx] = f2b(v);
            }
        }
    }
}

// ---------------------------------------------------------------------------
// f32 GEMM for the tiny temb path (M=32).
// ---------------------------------------------------------------------------
__global__ __launch_bounds__(256) void gemm_kernel(
    const float* __restrict__ A, int M, int K,
    const float* __restrict__ W, int ldw,
    const float* __restrict__ bias,
    const float* __restrict__ res,
    const float* __restrict__ pos,
    float* __restrict__ C, int N, int act)
{
    __shared__ float As[16][68];
    __shared__ float Ws[16][68];
    const int bm = blockIdx.y * 64;
    const int bn = blockIdx.x * 64;
    const int tid = threadIdx.x;
    const int tx = tid & 15, ty = tid >> 4;
    const int lr = tid >> 2;
    const int lk = (tid & 3) << 2;
    float acc[4][4] = {};

    for (int k0 = 0; k0 < K; k0 += 16) {
        float4 av = make_float4(0.f, 0.f, 0.f, 0.f);
        if (bm + lr < M)
            av = *reinterpret_cast<const float4*>(A + (size_t)(bm + lr) * K + k0 + lk);
        const float4 wv = *reinterpret_cast<const float4*>(W + (size_t)(bn + lr) * ldw + k0 + lk);
        __syncthreads();
        As[lk + 0][lr] = av.x; As[lk + 1][lr] = av.y; As[lk + 2][lr] = av.z; As[lk + 3][lr] = av.w;
        Ws[lk + 0][lr] = wv.x; Ws[lk + 1][lr] = wv.y; Ws[lk + 2][lr] = wv.z; Ws[lk + 3][lr] = wv.w;
        __syncthreads();
        #pragma unroll
        for (int kk = 0; kk < 16; ++kk) {
            const float4 a4 = *reinterpret_cast<const float4*>(&As[kk][ty * 4]);
            const float4 b4 = *reinterpret_cast<const float4*>(&Ws[kk][tx * 4]);
            const float ar[4] = {a4.x, a4.y, a4.z, a4.w};
            const float br[4] = {b4.x, b4.y, b4.z, b4.w};
            #pragma unroll
            for (int i = 0; i < 4; ++i)
                #pragma unroll
                for (int j = 0; j < 4; ++j)
                    acc[i][j] = fmaf(ar[i], br[j], acc[i][j]);
        }
    }

    #pragma unroll
    for (int i = 0; i < 4; ++i) {
        const int row = bm + ty * 4 + i;
        if (row >= M) break;
        #pragma unroll
        for (int j = 0; j < 4; ++j) {
            const int col = bn + tx * 4 + j;
            float v = acc[i][j];
            if (bias) v += bias[col];
            if (pos)  v += pos[(size_t)(row & (LL - 1)) * N + col];
            if (act == 1) v = fmaxf(v, 0.f);
            else if (act == 2) v = v / (1.f + __expf(-v));
            if (res) v += res[(size_t)row * N + col];
            C[(size_t)row * N + col] = v;
        }
    }
}

// ---------------------------------------------------------------------------
// MFMA causal flash attention. Q,K,V,Qin bf16; Sout f32 = Qin + softmax(QK^T/8)V.
// Block: 64 q-rows x (head,batch). 4 waves x 16 q-rows. KV chunks of 64.
// K staged [key][d], V staged transposed [d][key], both XOR-swizzled.
// ---------------------------------------------------------------------------
__global__ __launch_bounds__(256) void mattn_kernel(
    const unsigned short* __restrict__ Q, const unsigned short* __restrict__ K,
    const unsigned short* __restrict__ V, const unsigned short* __restrict__ Qin,
    float* __restrict__ Sout)
{
    __shared__ unsigned short kT[4096];      // [64 key][64 d] swizzled
    __shared__ unsigned short vT[4096];      // [64 d][64 key] swizzled
    __shared__ unsigned short pl[4][1024];   // per-wave P [16 row][64 key] swizzled

    const int qt = blockIdx.x;   // 0..7
    const int h  = blockIdx.y;   // 0..7
    const int b  = blockIdx.z;   // 0..31
    const int tid = threadIdx.x, lane = tid & 63, wid = tid >> 6;
    const int fr = lane & 15, fq = lane >> 4;
    const int hc = h * HDD;

    // Q fragments in registers (A operand): row = fr, k = kk*32 + fq*8
    const size_t qrow = (size_t)b * LL + qt * 64 + wid * 16 + fr;
    short8 qf[2];
    qf[0] = *reinterpret_cast<const short8*>(Q + qrow * CHN + hc + fq * 8);
    qf[1] = *reinterpret_cast<const short8*>(Q + qrow * CHN + hc + 32 + fq * 8);

    f32x4 oacc[4];
    #pragma unroll
    for (int n = 0; n < 4; ++n) oacc[n] = (f32x4){0.f, 0.f, 0.f, 0.f};
    float mrow[4], lrow[4];
    #pragma unroll
    for (int r = 0; r < 4; ++r) { mrow[r] = -1e30f; lrow[r] = 0.f; }

    for (int ch = 0; ch <= qt; ++ch) {
        const size_t mbase = (size_t)b * LL + ch * 64;
        __syncthreads();  // prior QK/PV reads of kT/vT complete
        #pragma unroll
        for (int p = 0; p < 2; ++p) {
            const int c = p * 256 + tid;          // 0..511
            const int row = c >> 3, d0 = (c & 7) * 8;
            const short8 kx = *reinterpret_cast<const short8*>(K + (mbase + row) * CHN + hc + d0);
            *reinterpret_cast<short8*>(&kT[SWZ(row, d0)]) = kx;
            const short8 vx = *reinterpret_cast<const short8*>(V + (mbase + row) * CHN + hc + d0);
            #pragma unroll
            for (int j = 0; j < 8; ++j)
                vT[SWZ(d0 + j, row)] = (unsigned short)vx[j];
        }
        __syncthreads();

        // S = Q @ K^T  (16x64 per wave)
        f32x4 sacc[4];
        #pragma unroll
        for (int n = 0; n < 4; ++n) sacc[n] = (f32x4){0.f, 0.f, 0.f, 0.f};
        #pragma unroll
        for (int kk = 0; kk < 2; ++kk) {
            #pragma unroll
            for (int n = 0; n < 4; ++n) {
                const short8 kf = *reinterpret_cast<const short8*>(
                    &kT[SWZ(n * 16 + fr, kk * 32 + fq * 8)]);
                sacc[n] = __builtin_amdgcn_mfma_f32_16x16x32_bf16(qf[kk], kf, sacc[n], 0, 0, 0);
            }
        }

        const bool diag = (ch == qt);
        // online softmax: lane holds col fr (per n-tile), rows fq*4+r
        #pragma unroll
        for (int r = 0; r < 4; ++r) {
            float sv[4];
            #pragma unroll
            for (int n = 0; n < 4; ++n) {
                float v = sacc[n][r] * 0.125f;
                if (diag && (n * 16 + fr > wid * 16 + fq * 4 + r)) v = -1e30f;
                sv[n] = v;
            }
            float cm = fmaxf(fmaxf(sv[0], sv[1]), fmaxf(sv[2], sv[3]));
            cm = fmaxf(cm, __shfl_xor(cm, 1));
            cm = fmaxf(cm, __shfl_xor(cm, 2));
            cm = fmaxf(cm, __shfl_xor(cm, 4));
            cm = fmaxf(cm, __shfl_xor(cm, 8));
            const float mn = fmaxf(mrow[r], cm);
            const float f = __expf(mrow[r] - mn);
            mrow[r] = mn;
            float ps = 0.f;
            #pragma unroll
            for (int n = 0; n < 4; ++n) { sv[n] = __expf(sv[n] - mn); ps += sv[n]; }
            ps += __shfl_xor(ps, 1);
            ps += __shfl_xor(ps, 2);
            ps += __shfl_xor(ps, 4);
            ps += __shfl_xor(ps, 8);
            lrow[r] = lrow[r] * f + ps;
            #pragma unroll
            for (int n = 0; n < 4; ++n) {
                oacc[n][r] *= f;
                pl[wid][SWZ(fq * 4 + r, n * 16 + fr)] = f2b(sv[n]);
            }
        }

        // O += P @ V  (A = P rows, B = V^T rows)
        #pragma unroll
        for (int kk = 0; kk < 2; ++kk) {
            const short8 pa = *reinterpret_cast<const short8*>(
                &pl[wid][SWZ(fr, kk * 32 + fq * 8)]);
            #pragma unroll
            for (int n = 0; n < 4; ++n) {
                const short8 vf = *reinterpret_cast<const short8*>(
                    &vT[SWZ(n * 16 + fr, kk * 32 + fq * 8)]);
                oacc[n] = __builtin_amdgcn_mfma_f32_16x16x32_bf16(pa, vf, oacc[n], 0, 0, 0);
            }
        }
    }

    // epilogue: O/l + Qin residual (C layout: col = n*16+fr, row = fq*4+r)
    const size_t orow0 = (size_t)b * LL + qt * 64 + wid * 16 + fq * 4;
    #pragma unroll
    for (int r = 0; r < 4; ++r) {
        const float inv = 1.f / lrow[r];
        const size_t rowidx = (orow0 + r) * CHN + hc;
        #pragma unroll
        for (int n = 0; n < 4; ++n) {
            const int d = n * 16 + fr;
            Sout[rowidx + d] = oacc[n][r] * inv + b2f(Qin[rowidx + d]);
        }
    }
}

// ---------------------------------------------------------------------------
__global__ __launch_bounds__(256) void temb_embed_kernel(
    const int* __restrict__ t, float* __restrict__ T0)
{
    const int idx = blockIdx.x * 256 + threadIdx.x;
    const int b = idx >> 9, j = idx & 511;
    const float tv = (float)t[b];
    const int jj = (j < 256) ? j : j - 256;
    const float freq = __expf((float)jj * (-9.210340371976184f / 255.f));
    const float ang = tv * freq;
    T0[idx] = (j < 256) ? sinf(ang) : cosf(ang);
}

__global__ __launch_bounds__(256) void add_temb_kernel(
    const float* __restrict__ xin, const float* __restrict__ temb,
    unsigned short* __restrict__ out)
{
    const size_t i4 = (size_t)blockIdx.x * 256 + threadIdx.x;
    const size_t elem = i4 * 4;
    const int b = (int)(elem >> 18);
    const int c = (int)(elem & (CHN - 1));
    const float4 a = reinterpret_cast<const float4*>(xin)[i4];
    const float4 tv = *reinterpret_cast<const float4*>(temb + (size_t)b * CHN + c);
    ushort4 o;
    o.x = f2b(a.x + tv.x); o.y = f2b(a.y + tv.y);
    o.z = f2b(a.z + tv.z); o.w = f2b(a.w + tv.w);
    reinterpret_cast<ushort4*>(out)[i4] = o;
}

// ---------------------------------------------------------------------------
extern "C" void kernel_launch(void* const* d_in, const int* in_sizes, int n_in,
                              void* d_out, int out_size, void* d_ws, size_t ws_size,
                              hipStream_t stream)
{
    (void)in_sizes; (void)n_in; (void)out_size; (void)ws_size;
    const float* log_seqs = (const float*)d_in[0];
    const float* seqs_nxt = (const float*)d_in[1];
    const int*   tt       = (const int*)d_in[2];
    const float* qw  = (const float*)d_in[3];
    const float* qb  = (const float*)d_in[4];
    const float* kw  = (const float*)d_in[5];
    const float* kb  = (const float*)d_in[6];
    const float* vw  = (const float*)d_in[7];
    const float* vb  = (const float*)d_in[8];
    const float* ln1g = (const float*)d_in[9];
    const float* ln1b = (const float*)d_in[10];
    const float* ln2g = (const float*)d_in[11];
    const float* ln2b = (const float*)d_in[12];
    const float* c1w = (const float*)d_in[13];
    const float* c1b = (const float*)d_in[14];
    const float* c2w = (const float*)d_in[15];
    const float* c2b = (const float*)d_in[16];
    const float* posK = (const float*)d_in[17];
    const float* posV = (const float*)d_in[18];
    const float* lng = (const float*)d_in[19];
    const float* lnb = (const float*)d_in[20];
    const float* tw0 = (const float*)d_in[21];
    const float* tb0 = (const float*)d_in[22];
    const float* tw1 = (const float*)d_in[23];
    const float* tb1 = (const float*)d_in[24];
    const float* tw2 = (const float*)d_in[25];
    const float* tb2 = (const float*)d_in[26];
    const float* decw = (const float*)d_in[27];
    const float* decb = (const float*)d_in[28];

    const size_t SZ = (size_t)BB * LL * CHN;  // 8388608
    const int M = BB * LL;                    // 16384
    float* out = (float*)d_out;
    float* log_feats = out;
    float* dec = out + SZ;
    unsigned short* QBb = (unsigned short*)dec;        // Q bf16 until decoder
    unsigned short* VBb = (unsigned short*)log_feats;  // V' bf16 until final LN

    float* ws = (float*)d_ws;
    float* S = ws;                                            // SZ f32
    unsigned short* KBb = (unsigned short*)(ws + SZ);         // SZ bf16
    unsigned short* R0  = (unsigned short*)(ws + SZ + SZ / 2);
    unsigned short* R1  = (unsigned short*)(ws + 2 * SZ);
    unsigned short* WBu = (unsigned short*)(ws + 2 * SZ + SZ / 2);  // 3145728 bf16
    float* T0 = ws + 2 * SZ + SZ / 2 + 1572864;
    float* T1 = T0 + 32 * CHN;
    float* T2 = T1 + 32 * 2048;
    float* T3 = T2 + 32 * 2048;

    const size_t WQ = 0, WK = 524288, WV = 1048576, WC1 = 1572864,
                 WC2 = 2097152, WDEC = 2621440;

    auto cvt = [&](const float* x, unsigned short* y, int n) {
        cvt_kernel<<<(n / 4 + 255) / 256, 256, 0, stream>>>(x, y, n / 4);
    };
    auto mg = [&](const unsigned short* A, const unsigned short* W, int ldw,
                  const float* bias, const float* pos, const float* res,
                  float* outf, unsigned short* outb, int act) {
        mgemm_kernel<<<512, 256, 0, stream>>>(A, W, ldw, bias, pos, res, outf, outb, act);
    };
    auto gemm = [&](const float* A, int Mm, int K, const float* W, int ldw,
                    const float* bias, const float* res, const float* pos,
                    float* C, int N, int act) {
        dim3 grid(N / 64, (Mm + 63) / 64);
        gemm_kernel<<<grid, 256, 0, stream>>>(A, Mm, K, W, ldw, bias, res, pos, C, N, act);
    };

    cvt(qw,  WBu + WQ,  524288);
    cvt(kw,  WBu + WK,  524288);
    cvt(vw,  WBu + WV,  524288);
    cvt(c1w, WBu + WC1, 524288);
    cvt(c2w, WBu + WC2, 524288);
    cvt(decw, WBu + WDEC, 524288);
    cvt(log_seqs, R1, (int)SZ);  // layer-0 curb

    const float* cur = log_seqs;
    for (int i = 0; i < 2; ++i) {
        const size_t wo = (size_t)i * 262144;
        const size_t bo = (size_t)i * CHN;
        unsigned short* qinb = (i == 0) ? R0 : R1;
        unsigned short* curb = (i == 0) ? R1 : R0;
        unsigned short* smb  = qinb;
        unsigned short* hb   = curb;
        unsigned short* ncb  = (i == 0) ? qinb : nullptr;

        ln_kernel<<<M, 256, 0, stream>>>(cur, ln1g + bo, ln1b + bo, nullptr, qinb);
        mg(qinb, WBu + WQ + wo, 512, qb + bo, nullptr, nullptr, nullptr, QBb, 0);
        mg(curb, WBu + WK + wo, 512, kb + bo, posK, nullptr, nullptr, KBb, 0);
        mg(curb, WBu + WV + wo, 512, vb + bo, posV, nullptr, nullptr, VBb, 0);
        mattn_kernel<<<dim3(LL / 64, NHH, BB), 256, 0, stream>>>(QBb, KBb, VBb, qinb, S);
        ln_kernel<<<M, 256, 0, stream>>>(S, ln2g + bo, ln2b + bo, S, smb);
        mg(smb, WBu + WC1 + wo, 512, c1b + bo, nullptr, nullptr, nullptr, hb, 1);
        mg(hb, WBu + WC2 + wo, 512, c2b + bo, nullptr, S, S, ncb, 0);
        cur = S;
    }

    ln_kernel<<<M, 256, 0, stream>>>(S, lng, lnb, log_feats, R0);

    temb_embed_kernel<<<(BB * CHN) / 256, 256, 0, stream>>>(tt, T0);
    gemm(T0, BB, CHN, tw0, CHN, tb0, nullptr, nullptr, T1, 2048, 2);
    gemm(T1, BB, 2048, tw1, 2048, tb1, nullptr, nullptr, T2, 2048, 2);
    gemm(T2, BB, 2048, tw2, 2048, tb2, nullptr, nullptr, T3, CHN, 0);
    add_temb_kernel<<<(M * CHN / 4) / 256, 256, 0, stream>>>(seqs_nxt, T3, R1);

    mg(R0, WBu + WDEC, 1024, decb, nullptr, nullptr, dec, nullptr, 0);
    mg(R1, WBu + WDEC + 512, 1024, nullptr, nullptr, dec, dec, nullptr, 0);
}

// Round 4
// 800.297 us; speedup vs baseline: 2.9354x; 1.1867x over previous
//
#include <hip/hip_runtime.h>
#include <math.h>

#define BB 32
#define LL 512
#define CHN 512
#define NHH 8
#define HDD 64

typedef __attribute__((ext_vector_type(8))) short short8;
typedef __attribute__((ext_vector_type(4))) float f32x4;

__device__ __forceinline__ float b2f(unsigned short s) {
    union { unsigned int u; float f; } c; c.u = ((unsigned int)s) << 16; return c.f;
}
__device__ __forceinline__ unsigned short f2b(float f) {
    union { float f; unsigned int u; } c; c.f = f;
    return (unsigned short)((c.u + 0x7fffu + ((c.u >> 16) & 1u)) >> 16);
}

// swizzled ushort index for a [rows][64] bf16 LDS tile (breaks 128B-stride conflicts)
#define SWZ(row, col) ((((row) * 64 + (col))) ^ (((row) & 7) << 3))

// ---------------------------------------------------------------------------
// f32 -> bf16 bulk convert
// ---------------------------------------------------------------------------
__global__ __launch_bounds__(256) void cvt_kernel(
    const float* __restrict__ x, unsigned short* __restrict__ y, int n4)
{
    int i = blockIdx.x * 256 + threadIdx.x;
    if (i >= n4) return;
    const float4 v = reinterpret_cast<const float4*>(x)[i];
    ushort4 o;
    o.x = f2b(v.x); o.y = f2b(v.y); o.z = f2b(v.z); o.w = f2b(v.w);
    reinterpret_cast<ushort4*>(y)[i] = o;
}

// ---------------------------------------------------------------------------
// Row LayerNorm over CH=512 (eps=1e-8). Optional f32 and/or bf16 outputs.
// ---------------------------------------------------------------------------
__global__ __launch_bounds__(256) void ln_kernel(
    const float* __restrict__ x, const float* __restrict__ g,
    const float* __restrict__ b, float* __restrict__ yf,
    unsigned short* __restrict__ yb)
{
    const int row = blockIdx.x;
    const int tid = threadIdx.x;
    const size_t base = (size_t)row * CHN;
    float2 v = *reinterpret_cast<const float2*>(x + base + tid * 2);
    float s  = v.x + v.y;
    float ss = v.x * v.x + v.y * v.y;
    #pragma unroll
    for (int m = 1; m < 64; m <<= 1) {
        s  += __shfl_xor(s, m);
        ss += __shfl_xor(ss, m);
    }
    __shared__ float red[8];
    const int wave = tid >> 6;
    if ((tid & 63) == 0) { red[wave] = s; red[4 + wave] = ss; }
    __syncthreads();
    s  = red[0] + red[1] + red[2] + red[3];
    ss = red[4] + red[5] + red[6] + red[7];
    const float mean = s * (1.0f / CHN);
    const float var  = ss * (1.0f / CHN) - mean * mean;
    const float inv  = rsqrtf(var + 1e-8f);
    const int c = tid * 2;
    float2 o;
    o.x = (v.x - mean) * inv * g[c]     + b[c];
    o.y = (v.y - mean) * inv * g[c + 1] + b[c + 1];
    if (yf) *reinterpret_cast<float2*>(yf + base + c) = o;
    if (yb) {
        ushort2 ob; ob.x = f2b(o.x); ob.y = f2b(o.y);
        *reinterpret_cast<ushort2*>(yb + base + c) = ob;
    }
}

// ---------------------------------------------------------------------------
// bf16 MFMA GEMM: 128x128 tile, BK=32, 4 waves.
// ---------------------------------------------------------------------------
__device__ __forceinline__ void gl16(const unsigned short* g, unsigned short* l) {
    __builtin_amdgcn_global_load_lds(
        (const __attribute__((address_space(1))) unsigned int*)g,
        (__attribute__((address_space(3))) unsigned int*)l, 16, 0, 0);
}

__global__ __launch_bounds__(256) void mgemm_kernel(
    const unsigned short* __restrict__ A,
    const unsigned short* __restrict__ W, int ldw,
    const float* __restrict__ bias,
    const float* __restrict__ pos,
    const float* __restrict__ res,
    float* __restrict__ outf,
    unsigned short* __restrict__ outb,
    int act)
{
    __shared__ alignas(16) unsigned short lA[4096];
    __shared__ alignas(16) unsigned short lB[4096];

    const int tid  = threadIdx.x;
    const int lane = tid & 63;
    const int wid  = tid >> 6;

    const int bid = blockIdx.x;
    const int swz = (bid & 7) * 64 + (bid >> 3);
    const int by = swz >> 2, bx = swz & 3;
    const int bm = by * 128, bn = bx * 128;

    const unsigned short* aS0 = A + (size_t)(bm + lane) * 512 + wid * 8;
    const unsigned short* aS1 = A + (size_t)(bm + 64 + lane) * 512 + wid * 8;
    const unsigned short* wS0 = W + (size_t)(bn + lane) * ldw + wid * 8;
    const unsigned short* wS1 = W + (size_t)(bn + 64 + lane) * ldw + wid * 8;
    unsigned short* lA0 = lA + (wid * 128) * 8;
    unsigned short* lA1 = lA + (wid * 128 + 64) * 8;
    unsigned short* lB0 = lB + (wid * 128) * 8;
    unsigned short* lB1 = lB + (wid * 128 + 64) * 8;

    const int wr = wid >> 1, wc = wid & 1;
    const int fr = lane & 15;
    const int fq = lane >> 4;

    f32x4 acc[4][4];
    #pragma unroll
    for (int m = 0; m < 4; ++m)
        #pragma unroll
        for (int n = 0; n < 4; ++n)
            acc[m][n] = (f32x4){0.f, 0.f, 0.f, 0.f};

    const unsigned short* pa = lA + (fq * 128 + wr * 64 + fr) * 8;
    const unsigned short* pb = lB + (fq * 128 + wc * 64 + fr) * 8;

    for (int k0 = 0; k0 < 512; k0 += 32) {
        __syncthreads();
        gl16(aS0 + k0, lA0);
        gl16(aS1 + k0, lA1);
        gl16(wS0 + k0, lB0);
        gl16(wS1 + k0, lB1);
        __syncthreads();

        short8 aF[4], bF[4];
        #pragma unroll
        for (int m = 0; m < 4; ++m)
            aF[m] = *reinterpret_cast<const short8*>(pa + m * 128);
        #pragma unroll
        for (int n = 0; n < 4; ++n)
            bF[n] = *reinterpret_cast<const short8*>(pb + n * 128);
        #pragma unroll
        for (int m = 0; m < 4; ++m)
            #pragma unroll
            for (int n = 0; n < 4; ++n)
                acc[m][n] = __builtin_amdgcn_mfma_f32_16x16x32_bf16(
                    aF[m], bF[n], acc[m][n], 0, 0, 0);
    }

    const int row0 = bm + wr * 64, col0 = bn + wc * 64;
    #pragma unroll
    for (int m = 0; m < 4; ++m) {
        #pragma unroll
        for (int n = 0; n < 4; ++n) {
            const int col = col0 + n * 16 + fr;
            const float bia = bias ? bias[col] : 0.f;
            #pragma unroll
            for (int r = 0; r < 4; ++r) {
                const int row = row0 + m * 16 + fq * 4 + r;
                float v = acc[m][n][r] + bia;
                if (pos) v += pos[(size_t)(row & (LL - 1)) * CHN + col];
                if (act == 1) v = fmaxf(v, 0.f);
                const size_t idx = (size_t)row * CHN + col;
                if (res) v += res[idx];
                if (outf) outf[idx] = v;
                if (outb) outb[idx] = f2b(v);
            }
        }
    }
}

// ---------------------------------------------------------------------------
// Split-K small-M GEMM for the temb path: P[kz][c][r] = A[32,K-slice] @ W[c]
// Grid (N/256, K/128). Each thread owns one output column (32 row-accs in
// registers); A-slice in LDS read via same-address broadcast (conflict-free).
// ---------------------------------------------------------------------------
__global__ __launch_bounds__(256) void skgemm_kernel(
    const float* __restrict__ A, int K,
    const float* __restrict__ W, int N,
    float* __restrict__ P)
{
    __shared__ float As[32][128];
    const int tid = threadIdx.x;
    const int kz  = blockIdx.y;
    const int c   = blockIdx.x * 256 + tid;

    #pragma unroll
    for (int i = 0; i < 16; ++i) {
        const int idx = i * 256 + tid;
        const int r = idx >> 7, k = idx & 127;
        As[r][k] = A[(size_t)r * K + kz * 128 + k];
    }
    __syncthreads();

    float acc[32];
    #pragma unroll
    for (int r = 0; r < 32; ++r) acc[r] = 0.f;

    const float* wrow = W + (size_t)c * K + kz * 128;
    for (int k4 = 0; k4 < 32; ++k4) {
        const float4 w = reinterpret_cast<const float4*>(wrow)[k4];
        #pragma unroll
        for (int r = 0; r < 32; ++r) {
            const float4 a = *reinterpret_cast<const float4*>(&As[r][k4 * 4]);
            acc[r] = fmaf(w.x, a.x, fmaf(w.y, a.y, fmaf(w.z, a.z, fmaf(w.w, a.w, acc[r]))));
        }
    }

    float* pp = P + ((size_t)kz * N + c) * 32;
    #pragma unroll
    for (int r = 0; r < 32; ++r) pp[r] = acc[r];
}

// out[r*N+c] = act(sum_kz P[kz][c][r] + bias[c]);  act: 0=none 2=swish
__global__ __launch_bounds__(256) void skreduce_kernel(
    const float* __restrict__ P, int KS, const float* __restrict__ bias,
    float* __restrict__ out, int N, int act)
{
    const int idx = blockIdx.x * 256 + threadIdx.x;  // c*32 + r
    const int r = idx & 31, c = idx >> 5;
    float s = 0.f;
    for (int kz = 0; kz < KS; ++kz)
        s += P[(size_t)kz * N * 32 + idx];
    s += bias[c];
    if (act == 2) s = s / (1.f + __expf(-s));
    out[(size_t)r * N + c] = s;
}

// ---------------------------------------------------------------------------
// MFMA causal flash attention (unchanged from round 3).
// ---------------------------------------------------------------------------
__global__ __launch_bounds__(256) void mattn_kernel(
    const unsigned short* __restrict__ Q, const unsigned short* __restrict__ K,
    const unsigned short* __restrict__ V, const unsigned short* __restrict__ Qin,
    float* __restrict__ Sout)
{
    __shared__ unsigned short kT[4096];
    __shared__ unsigned short vT[4096];
    __shared__ unsigned short pl[4][1024];

    const int qt = blockIdx.x;
    const int h  = blockIdx.y;
    const int b  = blockIdx.z;
    const int tid = threadIdx.x, lane = tid & 63, wid = tid >> 6;
    const int fr = lane & 15, fq = lane >> 4;
    const int hc = h * HDD;

    const size_t qrow = (size_t)b * LL + qt * 64 + wid * 16 + fr;
    short8 qf[2];
    qf[0] = *reinterpret_cast<const short8*>(Q + qrow * CHN + hc + fq * 8);
    qf[1] = *reinterpret_cast<const short8*>(Q + qrow * CHN + hc + 32 + fq * 8);

    f32x4 oacc[4];
    #pragma unroll
    for (int n = 0; n < 4; ++n) oacc[n] = (f32x4){0.f, 0.f, 0.f, 0.f};
    float mrow[4], lrow[4];
    #pragma unroll
    for (int r = 0; r < 4; ++r) { mrow[r] = -1e30f; lrow[r] = 0.f; }

    for (int ch = 0; ch <= qt; ++ch) {
        const size_t mbase = (size_t)b * LL + ch * 64;
        __syncthreads();
        #pragma unroll
        for (int p = 0; p < 2; ++p) {
            const int c = p * 256 + tid;
            const int row = c >> 3, d0 = (c & 7) * 8;
            const short8 kx = *reinterpret_cast<const short8*>(K + (mbase + row) * CHN + hc + d0);
            *reinterpret_cast<short8*>(&kT[SWZ(row, d0)]) = kx;
            const short8 vx = *reinterpret_cast<const short8*>(V + (mbase + row) * CHN + hc + d0);
            #pragma unroll
            for (int j = 0; j < 8; ++j)
                vT[SWZ(d0 + j, row)] = (unsigned short)vx[j];
        }
        __syncthreads();

        f32x4 sacc[4];
        #pragma unroll
        for (int n = 0; n < 4; ++n) sacc[n] = (f32x4){0.f, 0.f, 0.f, 0.f};
        #pragma unroll
        for (int kk = 0; kk < 2; ++kk) {
            #pragma unroll
            for (int n = 0; n < 4; ++n) {
                const short8 kf = *reinterpret_cast<const short8*>(
                    &kT[SWZ(n * 16 + fr, kk * 32 + fq * 8)]);
                sacc[n] = __builtin_amdgcn_mfma_f32_16x16x32_bf16(qf[kk], kf, sacc[n], 0, 0, 0);
            }
        }

        const bool diag = (ch == qt);
        #pragma unroll
        for (int r = 0; r < 4; ++r) {
            float sv[4];
            #pragma unroll
            for (int n = 0; n < 4; ++n) {
                float v = sacc[n][r] * 0.125f;
                if (diag && (n * 16 + fr > wid * 16 + fq * 4 + r)) v = -1e30f;
                sv[n] = v;
            }
            float cm = fmaxf(fmaxf(sv[0], sv[1]), fmaxf(sv[2], sv[3]));
            cm = fmaxf(cm, __shfl_xor(cm, 1));
            cm = fmaxf(cm, __shfl_xor(cm, 2));
            cm = fmaxf(cm, __shfl_xor(cm, 4));
            cm = fmaxf(cm, __shfl_xor(cm, 8));
            const float mn = fmaxf(mrow[r], cm);
            const float f = __expf(mrow[r] - mn);
            mrow[r] = mn;
            float ps = 0.f;
            #pragma unroll
            for (int n = 0; n < 4; ++n) { sv[n] = __expf(sv[n] - mn); ps += sv[n]; }
            ps += __shfl_xor(ps, 1);
            ps += __shfl_xor(ps, 2);
            ps += __shfl_xor(ps, 4);
            ps += __shfl_xor(ps, 8);
            lrow[r] = lrow[r] * f + ps;
            #pragma unroll
            for (int n = 0; n < 4; ++n) {
                oacc[n][r] *= f;
                pl[wid][SWZ(fq * 4 + r, n * 16 + fr)] = f2b(sv[n]);
            }
        }

        #pragma unroll
        for (int kk = 0; kk < 2; ++kk) {
            const short8 pa = *reinterpret_cast<const short8*>(
                &pl[wid][SWZ(fr, kk * 32 + fq * 8)]);
            #pragma unroll
            for (int n = 0; n < 4; ++n) {
                const short8 vf = *reinterpret_cast<const short8*>(
                    &vT[SWZ(n * 16 + fr, kk * 32 + fq * 8)]);
                oacc[n] = __builtin_amdgcn_mfma_f32_16x16x32_bf16(pa, vf, oacc[n], 0, 0, 0);
            }
        }
    }

    const size_t orow0 = (size_t)b * LL + qt * 64 + wid * 16 + fq * 4;
    #pragma unroll
    for (int r = 0; r < 4; ++r) {
        const float inv = 1.f / lrow[r];
        const size_t rowidx = (orow0 + r) * CHN + hc;
        #pragma unroll
        for (int n = 0; n < 4; ++n) {
            const int d = n * 16 + fr;
            Sout[rowidx + d] = oacc[n][r] * inv + b2f(Qin[rowidx + d]);
        }
    }
}

// ---------------------------------------------------------------------------
__global__ __launch_bounds__(256) void temb_embed_kernel(
    const int* __restrict__ t, float* __restrict__ T0)
{
    const int idx = blockIdx.x * 256 + threadIdx.x;
    const int b = idx >> 9, j = idx & 511;
    const float tv = (float)t[b];
    const int jj = (j < 256) ? j : j - 256;
    const float freq = __expf((float)jj * (-9.210340371976184f / 255.f));
    const float ang = tv * freq;
    T0[idx] = (j < 256) ? sinf(ang) : cosf(ang);
}

__global__ __launch_bounds__(256) void add_temb_kernel(
    const float* __restrict__ xin, const float* __restrict__ temb,
    unsigned short* __restrict__ out)
{
    const size_t i4 = (size_t)blockIdx.x * 256 + threadIdx.x;
    const size_t elem = i4 * 4;
    const int b = (int)(elem >> 18);
    const int c = (int)(elem & (CHN - 1));
    const float4 a = reinterpret_cast<const float4*>(xin)[i4];
    const float4 tv = *reinterpret_cast<const float4*>(temb + (size_t)b * CHN + c);
    ushort4 o;
    o.x = f2b(a.x + tv.x); o.y = f2b(a.y + tv.y);
    o.z = f2b(a.z + tv.z); o.w = f2b(a.w + tv.w);
    reinterpret_cast<ushort4*>(out)[i4] = o;
}

// ---------------------------------------------------------------------------
extern "C" void kernel_launch(void* const* d_in, const int* in_sizes, int n_in,
                              void* d_out, int out_size, void* d_ws, size_t ws_size,
                              hipStream_t stream)
{
    (void)in_sizes; (void)n_in; (void)out_size; (void)ws_size;
    const float* log_seqs = (const float*)d_in[0];
    const float* seqs_nxt = (const float*)d_in[1];
    const int*   tt       = (const int*)d_in[2];
    const float* qw  = (const float*)d_in[3];
    const float* qb  = (const float*)d_in[4];
    const float* kw  = (const float*)d_in[5];
    const float* kb  = (const float*)d_in[6];
    const float* vw  = (const float*)d_in[7];
    const float* vb  = (const float*)d_in[8];
    const float* ln1g = (const float*)d_in[9];
    const float* ln1b = (const float*)d_in[10];
    const float* ln2g = (const float*)d_in[11];
    const float* ln2b = (const float*)d_in[12];
    const float* c1w = (const float*)d_in[13];
    const float* c1b = (const float*)d_in[14];
    const float* c2w = (const float*)d_in[15];
    const float* c2b = (const float*)d_in[16];
    const float* posK = (const float*)d_in[17];
    const float* posV = (const float*)d_in[18];
    const float* lng = (const float*)d_in[19];
    const float* lnb = (const float*)d_in[20];
    const float* tw0 = (const float*)d_in[21];
    const float* tb0 = (const float*)d_in[22];
    const float* tw1 = (const float*)d_in[23];
    const float* tb1 = (const float*)d_in[24];
    const float* tw2 = (const float*)d_in[25];
    const float* tb2 = (const float*)d_in[26];
    const float* decw = (const float*)d_in[27];
    const float* decb = (const float*)d_in[28];

    const size_t SZ = (size_t)BB * LL * CHN;  // 8388608
    const int M = BB * LL;                    // 16384
    float* out = (float*)d_out;
    float* log_feats = out;
    float* dec = out + SZ;
    unsigned short* QBb = (unsigned short*)dec;        // Q bf16 until decoder
    unsigned short* VBb = (unsigned short*)log_feats;  // V' bf16 until final LN

    float* ws = (float*)d_ws;
    float* S = ws;                                            // SZ f32
    unsigned short* KBb = (unsigned short*)(ws + SZ);         // SZ bf16
    unsigned short* R0  = (unsigned short*)(ws + SZ + SZ / 2);
    unsigned short* R1  = (unsigned short*)(ws + 2 * SZ);
    unsigned short* WBu = (unsigned short*)(ws + 2 * SZ + SZ / 2);  // 3145728 bf16
    float* T0 = ws + 2 * SZ + SZ / 2 + 1572864;
    float* T1 = T0 + 32 * CHN;
    float* T2 = T1 + 32 * 2048;
    float* T3 = T2 + 32 * 2048;
    float* P  = S;   // split-K partials (S is dead after the final LN)

    const size_t WQ = 0, WK = 524288, WV = 1048576, WC1 = 1572864,
                 WC2 = 2097152, WDEC = 2621440;

    auto cvt = [&](const float* x, unsigned short* y, int n) {
        cvt_kernel<<<(n / 4 + 255) / 256, 256, 0, stream>>>(x, y, n / 4);
    };
    auto mg = [&](const unsigned short* A, const unsigned short* W, int ldw,
                  const float* bias, const float* pos, const float* res,
                  float* outf, unsigned short* outb, int act) {
        mgemm_kernel<<<512, 256, 0, stream>>>(A, W, ldw, bias, pos, res, outf, outb, act);
    };
    auto skg = [&](const float* A, int K, const float* W, int N,
                   const float* bias, float* o, int act) {
        skgemm_kernel<<<dim3(N / 256, K / 128), 256, 0, stream>>>(A, K, W, N, P);
        skreduce_kernel<<<(N * 32) / 256, 256, 0, stream>>>(P, K / 128, bias, o, N, act);
    };

    cvt(qw,  WBu + WQ,  524288);
    cvt(kw,  WBu + WK,  524288);
    cvt(vw,  WBu + WV,  524288);
    cvt(c1w, WBu + WC1, 524288);
    cvt(c2w, WBu + WC2, 524288);
    cvt(decw, WBu + WDEC, 524288);
    cvt(log_seqs, R1, (int)SZ);  // layer-0 curb

    const float* cur = log_seqs;
    for (int i = 0; i < 2; ++i) {
        const size_t wo = (size_t)i * 262144;
        const size_t bo = (size_t)i * CHN;
        unsigned short* qinb = (i == 0) ? R0 : R1;
        unsigned short* curb = (i == 0) ? R1 : R0;
        unsigned short* smb  = qinb;
        unsigned short* hb   = curb;
        unsigned short* ncb  = (i == 0) ? qinb : nullptr;

        ln_kernel<<<M, 256, 0, stream>>>(cur, ln1g + bo, ln1b + bo, nullptr, qinb);
        mg(qinb, WBu + WQ + wo, 512, qb + bo, nullptr, nullptr, nullptr, QBb, 0);
        mg(curb, WBu + WK + wo, 512, kb + bo, posK, nullptr, nullptr, KBb, 0);
        mg(curb, WBu + WV + wo, 512, vb + bo, posV, nullptr, nullptr, VBb, 0);
        mattn_kernel<<<dim3(LL / 64, NHH, BB), 256, 0, stream>>>(QBb, KBb, VBb, qinb, S);
        ln_kernel<<<M, 256, 0, stream>>>(S, ln2g + bo, ln2b + bo, S, smb);
        mg(smb, WBu + WC1 + wo, 512, c1b + bo, nullptr, nullptr, nullptr, hb, 1);
        mg(hb, WBu + WC2 + wo, 512, c2b + bo, nullptr, S, S, ncb, 0);
        cur = S;
    }

    ln_kernel<<<M, 256, 0, stream>>>(S, lng, lnb, log_feats, R0);

    // temb path (S/P reuse is safe: S is dead from here on)
    temb_embed_kernel<<<(BB * CHN) / 256, 256, 0, stream>>>(tt, T0);
    skg(T0, 512, tw0, 2048, tb0, T1, 2);
    skg(T1, 2048, tw1, 2048, tb1, T2, 2);
    skg(T2, 2048, tw2, 512, tb2, T3, 0);
    add_temb_kernel<<<(M * CHN / 4) / 256, 256, 0, stream>>>(seqs_nxt, T3, R1);

    mg(R0, WBu + WDEC, 1024, decb, nullptr, nullptr, dec, nullptr, 0);
    mg(R1, WBu + WDEC + 512, 1024, nullptr, nullptr, dec, dec, nullptr, 0);
}

// Round 6
// 799.110 us; speedup vs baseline: 2.9398x; 1.0015x over previous
//
#include <hip/hip_runtime.h>
#include <math.h>

#define BB 32
#define LL 512
#define CHN 512
#define NHH 8
#define HDD 64

typedef __attribute__((ext_vector_type(8))) short short8;
typedef __attribute__((ext_vector_type(4))) float f32x4;

__device__ __forceinline__ float b2f(unsigned short s) {
    union { unsigned int u; float f; } c; c.u = ((unsigned int)s) << 16; return c.f;
}
__device__ __forceinline__ unsigned short f2b(float f) {
    union { float f; unsigned int u; } c; c.f = f;
    return (unsigned short)((c.u + 0x7fffu + ((c.u >> 16) & 1u)) >> 16);
}

// swizzled ushort index for a [rows][64] bf16 LDS tile (breaks 128B-stride conflicts)
#define SWZ(row, col) ((((row) * 64 + (col))) ^ (((row) & 7) << 3))

__device__ __forceinline__ void gl16(const unsigned short* g, unsigned short* l) {
    __builtin_amdgcn_global_load_lds(
        (const __attribute__((address_space(1))) unsigned int*)g,
        (__attribute__((address_space(3))) unsigned int*)l, 16, 0, 0);
}

// ---------------------------------------------------------------------------
// f32 -> bf16 bulk convert
// ---------------------------------------------------------------------------
__global__ __launch_bounds__(256) void cvt_kernel(
    const float* __restrict__ x, unsigned short* __restrict__ y, int n4)
{
    int i = blockIdx.x * 256 + threadIdx.x;
    if (i >= n4) return;
    const float4 v = reinterpret_cast<const float4*>(x)[i];
    ushort4 o;
    o.x = f2b(v.x); o.y = f2b(v.y); o.z = f2b(v.z); o.w = f2b(v.w);
    reinterpret_cast<ushort4*>(y)[i] = o;
}

// ---------------------------------------------------------------------------
// Row LayerNorm over CH=512 (eps=1e-8). Optional f32 and/or bf16 outputs.
// ---------------------------------------------------------------------------
__global__ __launch_bounds__(256) void ln_kernel(
    const float* __restrict__ x, const float* __restrict__ g,
    const float* __restrict__ b, float* __restrict__ yf,
    unsigned short* __restrict__ yb)
{
    const int row = blockIdx.x;
    const int tid = threadIdx.x;
    const size_t base = (size_t)row * CHN;
    float2 v = *reinterpret_cast<const float2*>(x + base + tid * 2);
    float s  = v.x + v.y;
    float ss = v.x * v.x + v.y * v.y;
    #pragma unroll
    for (int m = 1; m < 64; m <<= 1) {
        s  += __shfl_xor(s, m);
        ss += __shfl_xor(ss, m);
    }
    __shared__ float red[8];
    const int wave = tid >> 6;
    if ((tid & 63) == 0) { red[wave] = s; red[4 + wave] = ss; }
    __syncthreads();
    s  = red[0] + red[1] + red[2] + red[3];
    ss = red[4] + red[5] + red[6] + red[7];
    const float mean = s * (1.0f / CHN);
    const float var  = ss * (1.0f / CHN) - mean * mean;
    const float inv  = rsqrtf(var + 1e-8f);
    const int c = tid * 2;
    float2 o;
    o.x = (v.x - mean) * inv * g[c]     + b[c];
    o.y = (v.y - mean) * inv * g[c + 1] + b[c + 1];
    if (yf) *reinterpret_cast<float2*>(yf + base + c) = o;
    if (yb) {
        ushort2 ob; ob.x = f2b(o.x); ob.y = f2b(o.y);
        *reinterpret_cast<ushort2*>(yb + base + c) = ob;
    }
}

// ---------------------------------------------------------------------------
// bf16 MFMA GEMM: 128x128 tile, BK=32, 4 waves, 2-phase double-buffered
// pipeline (stage next K-step under current MFMA; one barrier per step).
// outbt != null -> write transposed bf16: VT[(row>>9)*512 + col][row&511]
// (V^T layout [b][col=h*64+d][l], stride per batch = 512 rows).
// ---------------------------------------------------------------------------
__global__ __launch_bounds__(256) void mgemm_kernel(
    const unsigned short* __restrict__ A,
    const unsigned short* __restrict__ W, int ldw,
    const float* __restrict__ bias,
    const float* __restrict__ pos,
    const float* __restrict__ res,
    float* __restrict__ outf,
    unsigned short* __restrict__ outb,
    unsigned short* __restrict__ outbt,
    int act)
{
    __shared__ alignas(16) unsigned short lA[2][4096];
    __shared__ alignas(16) unsigned short lB[2][4096];

    const int tid  = threadIdx.x;
    const int lane = tid & 63;
    const int wid  = tid >> 6;

    const int bid = blockIdx.x;
    const int swz = (bid & 7) * 64 + (bid >> 3);
    const int by = swz >> 2, bx = swz & 3;
    const int bm = by * 128, bn = bx * 128;

    const unsigned short* aS0 = A + (size_t)(bm + lane) * 512 + wid * 8;
    const unsigned short* aS1 = A + (size_t)(bm + 64 + lane) * 512 + wid * 8;
    const unsigned short* wS0 = W + (size_t)(bn + lane) * ldw + wid * 8;
    const unsigned short* wS1 = W + (size_t)(bn + 64 + lane) * ldw + wid * 8;

    const int wr = wid >> 1, wc = wid & 1;
    const int fr = lane & 15;
    const int fq = lane >> 4;

    f32x4 acc[4][4];
    #pragma unroll
    for (int m = 0; m < 4; ++m)
        #pragma unroll
        for (int n = 0; n < 4; ++n)
            acc[m][n] = (f32x4){0.f, 0.f, 0.f, 0.f};

    #define MG_STAGE(buf, k0)                                   \
        do {                                                    \
            gl16(aS0 + (k0), &lA[buf][wid * 1024]);             \
            gl16(aS1 + (k0), &lA[buf][wid * 1024 + 512]);       \
            gl16(wS0 + (k0), &lB[buf][wid * 1024]);             \
            gl16(wS1 + (k0), &lB[buf][wid * 1024 + 512]);       \
        } while (0)

    MG_STAGE(0, 0);
    __syncthreads();

    #pragma unroll
    for (int t = 0; t < 16; ++t) {
        const int cur = t & 1;
        if (t < 15) MG_STAGE(cur ^ 1, (t + 1) * 32);
        const unsigned short* pa = &lA[cur][(fq * 128 + wr * 64 + fr) * 8];
        const unsigned short* pb = &lB[cur][(fq * 128 + wc * 64 + fr) * 8];
        short8 aF[4], bF[4];
        #pragma unroll
        for (int m = 0; m < 4; ++m)
            aF[m] = *reinterpret_cast<const short8*>(pa + m * 128);
        #pragma unroll
        for (int n = 0; n < 4; ++n)
            bF[n] = *reinterpret_cast<const short8*>(pb + n * 128);
        #pragma unroll
        for (int m = 0; m < 4; ++m)
            #pragma unroll
            for (int n = 0; n < 4; ++n)
                acc[m][n] = __builtin_amdgcn_mfma_f32_16x16x32_bf16(
                    aF[m], bF[n], acc[m][n], 0, 0, 0);
        __syncthreads();
    }
    #undef MG_STAGE

    const int row0 = bm + wr * 64, col0 = bn + wc * 64;
    #pragma unroll
    for (int m = 0; m < 4; ++m) {
        #pragma unroll
        for (int n = 0; n < 4; ++n) {
            const int col = col0 + n * 16 + fr;
            const float bia = bias ? bias[col] : 0.f;
            #pragma unroll
            for (int r = 0; r < 4; ++r) {
                const int row = row0 + m * 16 + fq * 4 + r;
                float v = acc[m][n][r] + bia;
                if (pos) v += pos[(size_t)(row & (LL - 1)) * CHN + col];
                if (act == 1) v = fmaxf(v, 0.f);
                const size_t idx = (size_t)row * CHN + col;
                if (res) v += res[idx];
                if (outf) outf[idx] = v;
                if (outb) outb[idx] = f2b(v);
                if (outbt)
                    outbt[((size_t)(row >> 9) * 512 + col) * 512 + (row & 511)] = f2b(v);
            }
        }
    }
}

// ---------------------------------------------------------------------------
// Split-K small-M GEMM for the temb path.
// ---------------------------------------------------------------------------
__global__ __launch_bounds__(256) void skgemm_kernel(
    const float* __restrict__ A, int K,
    const float* __restrict__ W, int N,
    float* __restrict__ P)
{
    __shared__ float As[32][128];
    const int tid = threadIdx.x;
    const int kz  = blockIdx.y;
    const int c   = blockIdx.x * 256 + tid;

    #pragma unroll
    for (int i = 0; i < 16; ++i) {
        const int idx = i * 256 + tid;
        const int r = idx >> 7, k = idx & 127;
        As[r][k] = A[(size_t)r * K + kz * 128 + k];
    }
    __syncthreads();

    float acc[32];
    #pragma unroll
    for (int r = 0; r < 32; ++r) acc[r] = 0.f;

    const float* wrow = W + (size_t)c * K + kz * 128;
    for (int k4 = 0; k4 < 32; ++k4) {
        const float4 w = reinterpret_cast<const float4*>(wrow)[k4];
        #pragma unroll
        for (int r = 0; r < 32; ++r) {
            const float4 a = *reinterpret_cast<const float4*>(&As[r][k4 * 4]);
            acc[r] = fmaf(w.x, a.x, fmaf(w.y, a.y, fmaf(w.z, a.z, fmaf(w.w, a.w, acc[r]))));
        }
    }

    float* pp = P + ((size_t)kz * N + c) * 32;
    #pragma unroll
    for (int r = 0; r < 32; ++r) pp[r] = acc[r];
}

__global__ __launch_bounds__(256) void skreduce_kernel(
    const float* __restrict__ P, int KS, const float* __restrict__ bias,
    float* __restrict__ out, int N, int act)
{
    const int idx = blockIdx.x * 256 + threadIdx.x;
    const int r = idx & 31, c = idx >> 5;
    float s = 0.f;
    for (int kz = 0; kz < KS; ++kz)
        s += P[(size_t)kz * N * 32 + idx];
    s += bias[c];
    if (act == 2) s = s / (1.f + __expf(-s));
    out[(size_t)r * N + c] = s;
}

// ---------------------------------------------------------------------------
// MFMA causal flash attention, v2.
// Q,K [row][512] bf16; VT [b*8+h][64 d][512 key] bf16; Qin bf16; Sout f32.
// K and V^T chunks staged via global_load_lds with PRE-SWIZZLED source
// columns (linear LDS dest, wave-uniform base); double-buffered.
// ---------------------------------------------------------------------------
__global__ __launch_bounds__(256) void mattn_kernel(
    const unsigned short* __restrict__ Q, const unsigned short* __restrict__ K,
    const unsigned short* __restrict__ VT, const unsigned short* __restrict__ Qin,
    float* __restrict__ Sout)
{
    __shared__ alignas(16) unsigned short kT[2][4096];
    __shared__ alignas(16) unsigned short vT[2][4096];
    __shared__ unsigned short pl[4][1024];

    const int qt = blockIdx.x;
    const int h  = blockIdx.y;
    const int b  = blockIdx.z;
    const int tid = threadIdx.x, lane = tid & 63, wid = tid >> 6;
    const int fr = lane & 15, fq = lane >> 4;
    const int hc = h * HDD;

    // per-thread pre-swizzled staging sources:
    // chunk = p*256+tid; row = chunk>>3; jj = chunk&7; src col block = jj^(row&7)
    const int c0i = tid, c1i = 256 + tid;
    const int r0s = c0i >> 3, j0s = c0i & 7, d0s = ((j0s ^ (r0s & 7)) << 3);
    const int r1s = c1i >> 3, j1s = c1i & 7, d1s = ((j1s ^ (r1s & 7)) << 3);
    const unsigned short* kS0 = K + (size_t)b * LL * CHN + (size_t)r0s * CHN + hc + d0s;
    const unsigned short* kS1 = K + (size_t)b * LL * CHN + (size_t)r1s * CHN + hc + d1s;
    const unsigned short* vS0 = VT + ((size_t)(b * NHH + h) * 64 + r0s) * 512 + d0s;
    const unsigned short* vS1 = VT + ((size_t)(b * NHH + h) * 64 + r1s) * 512 + d1s;

    // LDS dests are wave-uniform bases; HW writes base + lane*16B.
    #define AT_STAGE(buf, ch)                                              \
        do {                                                               \
            const int o = (ch) * 64;                                       \
            gl16(kS0 + (size_t)o * CHN, &kT[buf][wid * 512]);              \
            gl16(kS1 + (size_t)o * CHN, &kT[buf][2048 + wid * 512]);       \
            gl16(vS0 + o, &vT[buf][wid * 512]);                            \
            gl16(vS1 + o, &vT[buf][2048 + wid * 512]);                     \
        } while (0)

    // Q fragments in registers: row = fr, k = kk*32 + fq*8
    const size_t qrow = (size_t)b * LL + qt * 64 + wid * 16 + fr;
    short8 qf[2];
    qf[0] = *reinterpret_cast<const short8*>(Q + qrow * CHN + hc + fq * 8);
    qf[1] = *reinterpret_cast<const short8*>(Q + qrow * CHN + hc + 32 + fq * 8);

    f32x4 oacc[4];
    #pragma unroll
    for (int n = 0; n < 4; ++n) oacc[n] = (f32x4){0.f, 0.f, 0.f, 0.f};
    float mrow[4], lrow[4];
    #pragma unroll
    for (int r = 0; r < 4; ++r) { mrow[r] = -1e30f; lrow[r] = 0.f; }

    AT_STAGE(0, 0);
    __syncthreads();

    for (int ch = 0; ch <= qt; ++ch) {
        const int cur = ch & 1;
        if (ch < qt) AT_STAGE(cur ^ 1, ch + 1);

        // S = Q @ K^T  (16x64 per wave)
        f32x4 sacc[4];
        #pragma unroll
        for (int n = 0; n < 4; ++n) sacc[n] = (f32x4){0.f, 0.f, 0.f, 0.f};
        #pragma unroll
        for (int kk = 0; kk < 2; ++kk) {
            #pragma unroll
            for (int n = 0; n < 4; ++n) {
                const short8 kf = *reinterpret_cast<const short8*>(
                    &kT[cur][SWZ(n * 16 + fr, kk * 32 + fq * 8)]);
                sacc[n] = __builtin_amdgcn_mfma_f32_16x16x32_bf16(qf[kk], kf, sacc[n], 0, 0, 0);
            }
        }

        const bool diag = (ch == qt);
        #pragma unroll
        for (int r = 0; r < 4; ++r) {
            float sv[4];
            #pragma unroll
            for (int n = 0; n < 4; ++n) {
                float v = sacc[n][r] * 0.125f;
                if (diag && (n * 16 + fr > wid * 16 + fq * 4 + r)) v = -1e30f;
                sv[n] = v;
            }
            float cm = fmaxf(fmaxf(sv[0], sv[1]), fmaxf(sv[2], sv[3]));
            cm = fmaxf(cm, __shfl_xor(cm, 1));
            cm = fmaxf(cm, __shfl_xor(cm, 2));
            cm = fmaxf(cm, __shfl_xor(cm, 4));
            cm = fmaxf(cm, __shfl_xor(cm, 8));
            const float mn = fmaxf(mrow[r], cm);
            const float f = __expf(mrow[r] - mn);
            mrow[r] = mn;
            float ps = 0.f;
            #pragma unroll
            for (int n = 0; n < 4; ++n) { sv[n] = __expf(sv[n] - mn); ps += sv[n]; }
            ps += __shfl_xor(ps, 1);
            ps += __shfl_xor(ps, 2);
            ps += __shfl_xor(ps, 4);
            ps += __shfl_xor(ps, 8);
            lrow[r] = lrow[r] * f + ps;
            #pragma unroll
            for (int n = 0; n < 4; ++n) {
                oacc[n][r] *= f;
                pl[wid][SWZ(fq * 4 + r, n * 16 + fr)] = f2b(sv[n]);
            }
        }

        // O += P @ V  (B-frag from vT = V^T rows)
        #pragma unroll
        for (int kk = 0; kk < 2; ++kk) {
            const short8 pa = *reinterpret_cast<const short8*>(
                &pl[wid][SWZ(fr, kk * 32 + fq * 8)]);
            #pragma unroll
            for (int n = 0; n < 4; ++n) {
                const short8 vf = *reinterpret_cast<const short8*>(
                    &vT[cur][SWZ(n * 16 + fr, kk * 32 + fq * 8)]);
                oacc[n] = __builtin_amdgcn_mfma_f32_16x16x32_bf16(pa, vf, oacc[n], 0, 0, 0);
            }
        }
        __syncthreads();  // drain next-chunk staging; protect cur for overwrite
    }
    #undef AT_STAGE

    const size_t orow0 = (size_t)b * LL + qt * 64 + wid * 16 + fq * 4;
    #pragma unroll
    for (int r = 0; r < 4; ++r) {
        const float inv = 1.f / lrow[r];
        const size_t rowidx = (orow0 + r) * CHN + hc;
        #pragma unroll
        for (int n = 0; n < 4; ++n) {
            const int d = n * 16 + fr;
            Sout[rowidx + d] = oacc[n][r] * inv + b2f(Qin[rowidx + d]);
        }
    }
}

// ---------------------------------------------------------------------------
__global__ __launch_bounds__(256) void temb_embed_kernel(
    const int* __restrict__ t, float* __restrict__ T0)
{
    const int idx = blockIdx.x * 256 + threadIdx.x;
    const int b = idx >> 9, j = idx & 511;
    const float tv = (float)t[b];
    const int jj = (j < 256) ? j : j - 256;
    const float freq = __expf((float)jj * (-9.210340371976184f / 255.f));
    const float ang = tv * freq;
    T0[idx] = (j < 256) ? sinf(ang) : cosf(ang);
}

__global__ __launch_bounds__(256) void add_temb_kernel(
    const float* __restrict__ xin, const float* __restrict__ temb,
    unsigned short* __restrict__ out)
{
    const size_t i4 = (size_t)blockIdx.x * 256 + threadIdx.x;
    const size_t elem = i4 * 4;
    const int b = (int)(elem >> 18);
    const int c = (int)(elem & (CHN - 1));
    const float4 a = reinterpret_cast<const float4*>(xin)[i4];
    const float4 tv = *reinterpret_cast<const float4*>(temb + (size_t)b * CHN + c);
    ushort4 o;
    o.x = f2b(a.x + tv.x); o.y = f2b(a.y + tv.y);
    o.z = f2b(a.z + tv.z); o.w = f2b(a.w + tv.w);
    reinterpret_cast<ushort4*>(out)[i4] = o;
}

// ---------------------------------------------------------------------------
extern "C" void kernel_launch(void* const* d_in, const int* in_sizes, int n_in,
                              void* d_out, int out_size, void* d_ws, size_t ws_size,
                              hipStream_t stream)
{
    (void)in_sizes; (void)n_in; (void)out_size; (void)ws_size;
    const float* log_seqs = (const float*)d_in[0];
    const float* seqs_nxt = (const float*)d_in[1];
    const int*   tt       = (const int*)d_in[2];
    const float* qw  = (const float*)d_in[3];
    const float* qb  = (const float*)d_in[4];
    const float* kw  = (const float*)d_in[5];
    const float* kb  = (const float*)d_in[6];
    const float* vw  = (const float*)d_in[7];
    const float* vb  = (const float*)d_in[8];
    const float* ln1g = (const float*)d_in[9];
    const float* ln1b = (const float*)d_in[10];
    const float* ln2g = (const float*)d_in[11];
    const float* ln2b = (const float*)d_in[12];
    const float* c1w = (const float*)d_in[13];
    const float* c1b = (const float*)d_in[14];
    const float* c2w = (const float*)d_in[15];
    const float* c2b = (const float*)d_in[16];
    const float* posK = (const float*)d_in[17];
    const float* posV = (const float*)d_in[18];
    const float* lng = (const float*)d_in[19];
    const float* lnb = (const float*)d_in[20];
    const float* tw0 = (const float*)d_in[21];
    const float* tb0 = (const float*)d_in[22];
    const float* tw1 = (const float*)d_in[23];
    const float* tb1 = (const float*)d_in[24];
    const float* tw2 = (const float*)d_in[25];
    const float* tb2 = (const float*)d_in[26];
    const float* decw = (const float*)d_in[27];
    const float* decb = (const float*)d_in[28];

    const size_t SZ = (size_t)BB * LL * CHN;  // 8388608
    const int M = BB * LL;                    // 16384
    float* out = (float*)d_out;
    float* log_feats = out;
    float* dec = out + SZ;
    unsigned short* QBb = (unsigned short*)dec;        // Q bf16 until decoder
    unsigned short* VTb = (unsigned short*)log_feats;  // V^T bf16 until final LN

    float* ws = (float*)d_ws;
    float* S = ws;                                            // SZ f32
    unsigned short* KBb = (unsigned short*)(ws + SZ);         // SZ bf16
    unsigned short* R0  = (unsigned short*)(ws + SZ + SZ / 2);
    unsigned short* R1  = (unsigned short*)(ws + 2 * SZ);
    unsigned short* WBu = (unsigned short*)(ws + 2 * SZ + SZ / 2);  // 3145728 bf16
    float* T0 = ws + 2 * SZ + SZ / 2 + 1572864;
    float* T1 = T0 + 32 * CHN;
    float* T2 = T1 + 32 * 2048;
    float* T3 = T2 + 32 * 2048;
    float* P  = S;   // split-K partials (S is dead after the final LN)

    const size_t WQ = 0, WK = 524288, WV = 1048576, WC1 = 1572864,
                 WC2 = 2097152, WDEC = 2621440;

    auto cvt = [&](const float* x, unsigned short* y, int n) {
        cvt_kernel<<<(n / 4 + 255) / 256, 256, 0, stream>>>(x, y, n / 4);
    };
    auto mg = [&](const unsigned short* A, const unsigned short* W, int ldw,
                  const float* bias, const float* pos, const float* res,
                  float* outf, unsigned short* outb, unsigned short* outbt, int act) {
        mgemm_kernel<<<512, 256, 0, stream>>>(A, W, ldw, bias, pos, res,
                                              outf, outb, outbt, act);
    };
    auto skg = [&](const float* A, int K, const float* W, int N,
                   const float* bias, float* o, int act) {
        skgemm_kernel<<<dim3(N / 256, K / 128), 256, 0, stream>>>(A, K, W, N, P);
        skreduce_kernel<<<(N * 32) / 256, 256, 0, stream>>>(P, K / 128, bias, o, N, act);
    };

    cvt(qw,  WBu + WQ,  524288);
    cvt(kw,  WBu + WK,  524288);
    cvt(vw,  WBu + WV,  524288);
    cvt(c1w, WBu + WC1, 524288);
    cvt(c2w, WBu + WC2, 524288);
    cvt(decw, WBu + WDEC, 524288);
    cvt(log_seqs, R1, (int)SZ);  // layer-0 curb

    const float* cur = log_seqs;
    for (int i = 0; i < 2; ++i) {
        const size_t wo = (size_t)i * 262144;
        const size_t bo = (size_t)i * CHN;
        unsigned short* qinb = (i == 0) ? R0 : R1;
        unsigned short* curb = (i == 0) ? R1 : R0;
        unsigned short* smb  = qinb;
        unsigned short* hb   = curb;
        unsigned short* ncb  = (i == 0) ? qinb : nullptr;

        ln_kernel<<<M, 256, 0, stream>>>(cur, ln1g + bo, ln1b + bo, nullptr, qinb);
        mg(qinb, WBu + WQ + wo, 512, qb + bo, nullptr, nullptr, nullptr, QBb, nullptr, 0);
        mg(curb, WBu + WK + wo, 512, kb + bo, posK, nullptr, nullptr, KBb, nullptr, 0);
        mg(curb, WBu + WV + wo, 512, vb + bo, posV, nullptr, nullptr, nullptr, VTb, 0);
        mattn_kernel<<<dim3(LL / 64, NHH, BB), 256, 0, stream>>>(QBb, KBb, VTb, qinb, S);
        ln_kernel<<<M, 256, 0, stream>>>(S, ln2g + bo, ln2b + bo, S, smb);
        mg(smb, WBu + WC1 + wo, 512, c1b + bo, nullptr, nullptr, nullptr, hb, nullptr, 1);
        mg(hb, WBu + WC2 + wo, 512, c2b + bo, nullptr, S, S, ncb, nullptr, 0);
        cur = S;
    }

    ln_kernel<<<M, 256, 0, stream>>>(S, lng, lnb, log_feats, R0);

    temb_embed_kernel<<<(BB * CHN) / 256, 256, 0, stream>>>(tt, T0);
    skg(T0, 512, tw0, 2048, tb0, T1, 2);
    skg(T1, 2048, tw1, 2048, tb1, T2, 2);
    skg(T2, 2048, tw2, 512, tb2, T3, 0);
    add_temb_kernel<<<(M * CHN / 4) / 256, 256, 0, stream>>>(seqs_nxt, T3, R1);

    mg(R0, WBu + WDEC, 1024, decb, nullptr, nullptr, dec, nullptr, nullptr, 0);
    mg(R1, WBu + WDEC + 512, 1024, nullptr, nullptr, dec, dec, nullptr, nullptr, 0);
}

// Round 7
// 764.870 us; speedup vs baseline: 3.0714x; 1.0448x over previous
//
#include <hip/hip_runtime.h>
#include <math.h>

#define BB 32
#define LL 512
#define CHN 512
#define NHH 8
#define HDD 64

typedef __attribute__((ext_vector_type(8))) short short8;
typedef __attribute__((ext_vector_type(4))) float f32x4;

__device__ __forceinline__ float b2f(unsigned short s) {
    union { unsigned int u; float f; } c; c.u = ((unsigned int)s) << 16; return c.f;
}
__device__ __forceinline__ unsigned short f2b(float f) {
    union { float f; unsigned int u; } c; c.f = f;
    return (unsigned short)((c.u + 0x7fffu + ((c.u >> 16) & 1u)) >> 16);
}

// swizzled ushort index for a [rows][64] bf16 LDS tile (breaks 128B-stride conflicts)
#define SWZ(row, col) ((((row) * 64 + (col))) ^ (((row) & 7) << 3))

__device__ __forceinline__ void gl16(const unsigned short* g, unsigned short* l) {
    __builtin_amdgcn_global_load_lds(
        (const __attribute__((address_space(1))) unsigned int*)g,
        (__attribute__((address_space(3))) unsigned int*)l, 16, 0, 0);
}

// ---------------------------------------------------------------------------
// f32 -> bf16 bulk converts
// ---------------------------------------------------------------------------
__global__ __launch_bounds__(256) void cvt_kernel(
    const float* __restrict__ x, unsigned short* __restrict__ y, int n4)
{
    int i = blockIdx.x * 256 + threadIdx.x;
    if (i >= n4) return;
    const float4 v = reinterpret_cast<const float4*>(x)[i];
    ushort4 o;
    o.x = f2b(v.x); o.y = f2b(v.y); o.z = f2b(v.z); o.w = f2b(v.w);
    reinterpret_cast<ushort4*>(y)[i] = o;
}

// 6 weight matrices (512x512 f32 each) -> contiguous bf16 slab
__global__ __launch_bounds__(256) void cvt6_kernel(
    const float* __restrict__ p0, const float* __restrict__ p1,
    const float* __restrict__ p2, const float* __restrict__ p3,
    const float* __restrict__ p4, const float* __restrict__ p5,
    unsigned short* __restrict__ y)
{
    const int j = blockIdx.y;
    const float* x = j == 0 ? p0 : j == 1 ? p1 : j == 2 ? p2
                   : j == 3 ? p3 : j == 4 ? p4 : p5;
    const int i = blockIdx.x * 256 + threadIdx.x;   // 0..131071 float4s
    const float4 v = reinterpret_cast<const float4*>(x)[i];
    ushort4 o;
    o.x = f2b(v.x); o.y = f2b(v.y); o.z = f2b(v.z); o.w = f2b(v.w);
    reinterpret_cast<ushort4*>(y + (size_t)j * 524288)[i] = o;
}

// ---------------------------------------------------------------------------
// Row LayerNorm over CH=512 (eps=1e-8). Optional f32 and/or bf16 outputs.
// ---------------------------------------------------------------------------
__global__ __launch_bounds__(256) void ln_kernel(
    const float* __restrict__ x, const float* __restrict__ g,
    const float* __restrict__ b, float* __restrict__ yf,
    unsigned short* __restrict__ yb)
{
    const int row = blockIdx.x;
    const int tid = threadIdx.x;
    const size_t base = (size_t)row * CHN;
    float2 v = *reinterpret_cast<const float2*>(x + base + tid * 2);
    float s  = v.x + v.y;
    float ss = v.x * v.x + v.y * v.y;
    #pragma unroll
    for (int m = 1; m < 64; m <<= 1) {
        s  += __shfl_xor(s, m);
        ss += __shfl_xor(ss, m);
    }
    __shared__ float red[8];
    const int wave = tid >> 6;
    if ((tid & 63) == 0) { red[wave] = s; red[4 + wave] = ss; }
    __syncthreads();
    s  = red[0] + red[1] + red[2] + red[3];
    ss = red[4] + red[5] + red[6] + red[7];
    const float mean = s * (1.0f / CHN);
    const float var  = ss * (1.0f / CHN) - mean * mean;
    const float inv  = rsqrtf(var + 1e-8f);
    const int c = tid * 2;
    float2 o;
    o.x = (v.x - mean) * inv * g[c]     + b[c];
    o.y = (v.y - mean) * inv * g[c + 1] + b[c + 1];
    if (yf) *reinterpret_cast<float2*>(yf + base + c) = o;
    if (yb) {
        ushort2 ob; ob.x = f2b(o.x); ob.y = f2b(o.y);
        *reinterpret_cast<ushort2*>(yb + base + c) = ob;
    }
}

// ---------------------------------------------------------------------------
// bf16 MFMA GEMM body: 128x128 tile, BK=32, 4 waves, depth-3 counted-vmcnt
// pipeline (T3/T4): STAGE(t+2) -> vmcnt(8) -> barrier -> ds_read -> lgkm(0)
// -> barrier -> MFMA. NT = K/32 steps; A2 != null supplies k >= 512 (dec).
// outbt: transposed bf16 write VT[(row>>9)*512 + col][row&511] as ushort4.
// ---------------------------------------------------------------------------
template <int NT>
__device__ __forceinline__ void gemm_body(
    const unsigned short* __restrict__ A,
    const unsigned short* __restrict__ A2,
    const unsigned short* __restrict__ W, int ldw,
    const float* __restrict__ bias,
    const float* __restrict__ pos,
    const float* __restrict__ res,
    float* __restrict__ outf,
    unsigned short* __restrict__ outb,
    unsigned short* __restrict__ outbt,
    int act, int bid)
{
    __shared__ alignas(16) unsigned short lA[3][4096];
    __shared__ alignas(16) unsigned short lB[3][4096];

    const int tid  = threadIdx.x;
    const int lane = tid & 63;
    const int wid  = tid >> 6;

    const int swz = (bid & 7) * 64 + (bid >> 3);
    const int by = swz >> 2, bx = swz & 3;
    const int bm = by * 128, bn = bx * 128;

    const unsigned short* Ax = A2 ? A2 : A;
    const unsigned short* aS0  = A  + (size_t)(bm + lane) * 512 + wid * 8;
    const unsigned short* aS1  = A  + (size_t)(bm + 64 + lane) * 512 + wid * 8;
    const unsigned short* a2S0 = Ax + (size_t)(bm + lane) * 512 + wid * 8;
    const unsigned short* a2S1 = Ax + (size_t)(bm + 64 + lane) * 512 + wid * 8;
    const unsigned short* wS0  = W + (size_t)(bn + lane) * ldw + wid * 8;
    const unsigned short* wS1  = W + (size_t)(bn + 64 + lane) * ldw + wid * 8;

    const int wr = wid >> 1, wc = wid & 1;
    const int fr = lane & 15;
    const int fq = lane >> 4;

    f32x4 acc[4][4];
    #pragma unroll
    for (int m = 0; m < 4; ++m)
        #pragma unroll
        for (int n = 0; n < 4; ++n)
            acc[m][n] = (f32x4){0.f, 0.f, 0.f, 0.f};

    #define MG_STAGE(buf, t)                                            \
        do {                                                            \
            const int k0 = ((t) & 15) * 32;                             \
            const unsigned short* s0 = ((t) < 16) ? aS0 : a2S0;         \
            const unsigned short* s1 = ((t) < 16) ? aS1 : a2S1;         \
            gl16(s0 + k0, &lA[buf][wid * 1024]);                        \
            gl16(s1 + k0, &lA[buf][wid * 1024 + 512]);                  \
            gl16(wS0 + (t) * 32, &lB[buf][wid * 1024]);                 \
            gl16(wS1 + (t) * 32, &lB[buf][wid * 1024 + 512]);           \
        } while (0)

    MG_STAGE(0, 0);
    MG_STAGE(1, 1);

    #pragma unroll
    for (int t = 0; t < NT; ++t) {
        const int cur = t % 3;
        if (t + 2 < NT) {
            MG_STAGE((t + 2) % 3, t + 2);
            asm volatile("s_waitcnt vmcnt(8)" ::: "memory");
        } else if (t + 1 < NT) {
            asm volatile("s_waitcnt vmcnt(4)" ::: "memory");
        } else {
            asm volatile("s_waitcnt vmcnt(0)" ::: "memory");
        }
        __builtin_amdgcn_s_barrier();

        const unsigned short* pa = &lA[cur][(fq * 128 + wr * 64 + fr) * 8];
        const unsigned short* pb = &lB[cur][(fq * 128 + wc * 64 + fr) * 8];
        short8 aF[4], bF[4];
        #pragma unroll
        for (int m = 0; m < 4; ++m)
            aF[m] = *reinterpret_cast<const short8*>(pa + m * 128);
        #pragma unroll
        for (int n = 0; n < 4; ++n)
            bF[n] = *reinterpret_cast<const short8*>(pb + n * 128);
        asm volatile("s_waitcnt lgkmcnt(0)" ::: "memory");
        __builtin_amdgcn_s_barrier();

        #pragma unroll
        for (int m = 0; m < 4; ++m)
            #pragma unroll
            for (int n = 0; n < 4; ++n)
                acc[m][n] = __builtin_amdgcn_mfma_f32_16x16x32_bf16(
                    aF[m], bF[n], acc[m][n], 0, 0, 0);
    }
    #undef MG_STAGE

    const int row0 = bm + wr * 64, col0 = bn + wc * 64;
    #pragma unroll
    for (int m = 0; m < 4; ++m) {
        #pragma unroll
        for (int n = 0; n < 4; ++n) {
            const int col = col0 + n * 16 + fr;
            const float bia = bias ? bias[col] : 0.f;
            ushort4 o4;
            #pragma unroll
            for (int r = 0; r < 4; ++r) {
                const int row = row0 + m * 16 + fq * 4 + r;
                float v = acc[m][n][r] + bia;
                if (pos) v += pos[(size_t)(row & (LL - 1)) * CHN + col];
                if (act == 1) v = fmaxf(v, 0.f);
                const size_t idx = (size_t)row * CHN + col;
                if (res) v += res[idx];
                if (outf) outf[idx] = v;
                if (outb) outb[idx] = f2b(v);
                ((unsigned short*)&o4)[r] = f2b(v);
            }
            if (outbt) {
                const int rw = row0 + m * 16 + fq * 4;   // 4-aligned, no 512-cross
                *reinterpret_cast<ushort4*>(
                    &outbt[((size_t)(rw >> 9) * 512 + col) * 512 + (rw & 511)]) = o4;
            }
        }
    }
}

__global__ __launch_bounds__(256) void mgemm_kernel(
    const unsigned short* __restrict__ A,
    const unsigned short* __restrict__ W, int ldw,
    const float* __restrict__ bias,
    const float* __restrict__ pos,
    const float* __restrict__ res,
    float* __restrict__ outf,
    unsigned short* __restrict__ outb,
    unsigned short* __restrict__ outbt,
    int act)
{
    gemm_body<16>(A, nullptr, W, ldw, bias, pos, res, outf, outb, outbt, act,
                  blockIdx.x);
}

// Q/K/V fused: blockIdx.y selects job (0=Q, 1=K, 2=V^T)
__global__ __launch_bounds__(256) void qkv_kernel(
    const unsigned short* __restrict__ qinb, const unsigned short* __restrict__ curb,
    const unsigned short* __restrict__ Wq, const unsigned short* __restrict__ Wk,
    const unsigned short* __restrict__ Wv,
    const float* __restrict__ qb, const float* __restrict__ kb,
    const float* __restrict__ vb,
    const float* __restrict__ posK, const float* __restrict__ posV,
    unsigned short* __restrict__ QBb, unsigned short* __restrict__ KBb,
    unsigned short* __restrict__ VTb)
{
    const int job = blockIdx.y;
    const unsigned short* A = (job == 0) ? qinb : curb;
    const unsigned short* W = (job == 0) ? Wq : (job == 1) ? Wk : Wv;
    const float* bias = (job == 0) ? qb : (job == 1) ? kb : vb;
    const float* pos  = (job == 0) ? nullptr : (job == 1) ? posK : posV;
    unsigned short* outb  = (job == 0) ? QBb : (job == 1) ? KBb : nullptr;
    unsigned short* outbt = (job == 2) ? VTb : nullptr;
    gemm_body<16>(A, nullptr, W, 512, bias, pos, nullptr, nullptr, outb, outbt, 0,
                  blockIdx.x);
}

// Decoder fused: dec = [log_feats | x_t] @ decw^T + decb  (K=1024, two A sources)
__global__ __launch_bounds__(256) void dec_kernel(
    const unsigned short* __restrict__ R0b, const unsigned short* __restrict__ R1b,
    const unsigned short* __restrict__ Wd, const float* __restrict__ decb,
    float* __restrict__ dec)
{
    gemm_body<32>(R0b, R1b, Wd, 1024, decb, nullptr, nullptr, dec, nullptr, nullptr,
                  0, blockIdx.x);
}

// ---------------------------------------------------------------------------
// Split-K small-M GEMM for the temb path.
// ---------------------------------------------------------------------------
__global__ __launch_bounds__(256) void skgemm_kernel(
    const float* __restrict__ A, int K,
    const float* __restrict__ W, int N,
    float* __restrict__ P)
{
    __shared__ float As[32][128];
    const int tid = threadIdx.x;
    const int kz  = blockIdx.y;
    const int c   = blockIdx.x * 256 + tid;

    #pragma unroll
    for (int i = 0; i < 16; ++i) {
        const int idx = i * 256 + tid;
        const int r = idx >> 7, k = idx & 127;
        As[r][k] = A[(size_t)r * K + kz * 128 + k];
    }
    __syncthreads();

    float acc[32];
    #pragma unroll
    for (int r = 0; r < 32; ++r) acc[r] = 0.f;

    const float* wrow = W + (size_t)c * K + kz * 128;
    for (int k4 = 0; k4 < 32; ++k4) {
        const float4 w = reinterpret_cast<const float4*>(wrow)[k4];
        #pragma unroll
        for (int r = 0; r < 32; ++r) {
            const float4 a = *reinterpret_cast<const float4*>(&As[r][k4 * 4]);
            acc[r] = fmaf(w.x, a.x, fmaf(w.y, a.y, fmaf(w.z, a.z, fmaf(w.w, a.w, acc[r]))));
        }
    }

    float* pp = P + ((size_t)kz * N + c) * 32;
    #pragma unroll
    for (int r = 0; r < 32; ++r) pp[r] = acc[r];
}

__global__ __launch_bounds__(256) void skreduce_kernel(
    const float* __restrict__ P, int KS, const float* __restrict__ bias,
    float* __restrict__ out, int N, int act)
{
    const int idx = blockIdx.x * 256 + threadIdx.x;
    const int r = idx & 31, c = idx >> 5;
    float s = 0.f;
    for (int kz = 0; kz < KS; ++kz)
        s += P[(size_t)kz * N * 32 + idx];
    s += bias[c];
    if (act == 2) s = s / (1.f + __expf(-s));
    out[(size_t)r * N + c] = s;
}

// ---------------------------------------------------------------------------
// MFMA causal flash attention (round-6 structure + defer-max T13).
// ---------------------------------------------------------------------------
__global__ __launch_bounds__(256) void mattn_kernel(
    const unsigned short* __restrict__ Q, const unsigned short* __restrict__ K,
    const unsigned short* __restrict__ VT, const unsigned short* __restrict__ Qin,
    float* __restrict__ Sout)
{
    __shared__ alignas(16) unsigned short kT[2][4096];
    __shared__ alignas(16) unsigned short vT[2][4096];
    __shared__ unsigned short pl[4][1024];

    const int qt = blockIdx.x;
    const int h  = blockIdx.y;
    const int b  = blockIdx.z;
    const int tid = threadIdx.x, lane = tid & 63, wid = tid >> 6;
    const int fr = lane & 15, fq = lane >> 4;
    const int hc = h * HDD;

    const int c0i = tid, c1i = 256 + tid;
    const int r0s = c0i >> 3, j0s = c0i & 7, d0s = ((j0s ^ (r0s & 7)) << 3);
    const int r1s = c1i >> 3, j1s = c1i & 7, d1s = ((j1s ^ (r1s & 7)) << 3);
    const unsigned short* kS0 = K + (size_t)b * LL * CHN + (size_t)r0s * CHN + hc + d0s;
    const unsigned short* kS1 = K + (size_t)b * LL * CHN + (size_t)r1s * CHN + hc + d1s;
    const unsigned short* vS0 = VT + ((size_t)(b * NHH + h) * 64 + r0s) * 512 + d0s;
    const unsigned short* vS1 = VT + ((size_t)(b * NHH + h) * 64 + r1s) * 512 + d1s;

    #define AT_STAGE(buf, ch)                                              \
        do {                                                               \
            const int o = (ch) * 64;                                       \
            gl16(kS0 + (size_t)o * CHN, &kT[buf][wid * 512]);              \
            gl16(kS1 + (size_t)o * CHN, &kT[buf][2048 + wid * 512]);       \
            gl16(vS0 + o, &vT[buf][wid * 512]);                            \
            gl16(vS1 + o, &vT[buf][2048 + wid * 512]);                     \
        } while (0)

    const size_t qrow = (size_t)b * LL + qt * 64 + wid * 16 + fr;
    short8 qf[2];
    qf[0] = *reinterpret_cast<const short8*>(Q + qrow * CHN + hc + fq * 8);
    qf[1] = *reinterpret_cast<const short8*>(Q + qrow * CHN + hc + 32 + fq * 8);

    f32x4 oacc[4];
    #pragma unroll
    for (int n = 0; n < 4; ++n) oacc[n] = (f32x4){0.f, 0.f, 0.f, 0.f};
    float mrow[4], lrow[4];
    #pragma unroll
    for (int r = 0; r < 4; ++r) { mrow[r] = -1e30f; lrow[r] = 0.f; }

    AT_STAGE(0, 0);
    __syncthreads();

    for (int ch = 0; ch <= qt; ++ch) {
        const int cur = ch & 1;
        if (ch < qt) AT_STAGE(cur ^ 1, ch + 1);

        f32x4 sacc[4];
        #pragma unroll
        for (int n = 0; n < 4; ++n) sacc[n] = (f32x4){0.f, 0.f, 0.f, 0.f};
        #pragma unroll
        for (int kk = 0; kk < 2; ++kk) {
            #pragma unroll
            for (int n = 0; n < 4; ++n) {
                const short8 kf = *reinterpret_cast<const short8*>(
                    &kT[cur][SWZ(n * 16 + fr, kk * 32 + fq * 8)]);
                sacc[n] = __builtin_amdgcn_mfma_f32_16x16x32_bf16(qf[kk], kf, sacc[n], 0, 0, 0);
            }
        }

        const bool diag = (ch == qt);
        #pragma unroll
        for (int r = 0; r < 4; ++r) {
            float sv[4];
            #pragma unroll
            for (int n = 0; n < 4; ++n) {
                float v = sacc[n][r] * 0.125f;
                if (diag && (n * 16 + fr > wid * 16 + fq * 4 + r)) v = -1e30f;
                sv[n] = v;
            }
            float cm = fmaxf(fmaxf(sv[0], sv[1]), fmaxf(sv[2], sv[3]));
            cm = fmaxf(cm, __shfl_xor(cm, 1));
            cm = fmaxf(cm, __shfl_xor(cm, 2));
            cm = fmaxf(cm, __shfl_xor(cm, 4));
            cm = fmaxf(cm, __shfl_xor(cm, 8));
            // T13 defer-max: keep old running max if growth <= 8 (wave-uniform)
            const bool defer = __all(cm - mrow[r] <= 8.f);
            const float mn = defer ? mrow[r] : fmaxf(mrow[r], cm);
            float ps = 0.f;
            #pragma unroll
            for (int n = 0; n < 4; ++n) { sv[n] = __expf(sv[n] - mn); ps += sv[n]; }
            ps += __shfl_xor(ps, 1);
            ps += __shfl_xor(ps, 2);
            ps += __shfl_xor(ps, 4);
            ps += __shfl_xor(ps, 8);
            if (defer) {
                lrow[r] += ps;
            } else {
                const float f = __expf(mrow[r] - mn);
                lrow[r] = lrow[r] * f + ps;
                mrow[r] = mn;
                #pragma unroll
                for (int n = 0; n < 4; ++n) oacc[n][r] *= f;
            }
            #pragma unroll
            for (int n = 0; n < 4; ++n)
                pl[wid][SWZ(fq * 4 + r, n * 16 + fr)] = f2b(sv[n]);
        }

        #pragma unroll
        for (int kk = 0; kk < 2; ++kk) {
            const short8 pa = *reinterpret_cast<const short8*>(
                &pl[wid][SWZ(fr, kk * 32 + fq * 8)]);
            #pragma unroll
            for (int n = 0; n < 4; ++n) {
                const short8 vf = *reinterpret_cast<const short8*>(
                    &vT[cur][SWZ(n * 16 + fr, kk * 32 + fq * 8)]);
                oacc[n] = __builtin_amdgcn_mfma_f32_16x16x32_bf16(pa, vf, oacc[n], 0, 0, 0);
            }
        }
        __syncthreads();
    }
    #undef AT_STAGE

    const size_t orow0 = (size_t)b * LL + qt * 64 + wid * 16 + fq * 4;
    #pragma unroll
    for (int r = 0; r < 4; ++r) {
        const float inv = 1.f / lrow[r];
        const size_t rowidx = (orow0 + r) * CHN + hc;
        #pragma unroll
        for (int n = 0; n < 4; ++n) {
            const int d = n * 16 + fr;
            Sout[rowidx + d] = oacc[n][r] * inv + b2f(Qin[rowidx + d]);
        }
    }
}

// ---------------------------------------------------------------------------
__global__ __launch_bounds__(256) void temb_embed_kernel(
    const int* __restrict__ t, float* __restrict__ T0)
{
    const int idx = blockIdx.x * 256 + threadIdx.x;
    const int b = idx >> 9, j = idx & 511;
    const float tv = (float)t[b];
    const int jj = (j < 256) ? j : j - 256;
    const float freq = __expf((float)jj * (-9.210340371976184f / 255.f));
    const float ang = tv * freq;
    T0[idx] = (j < 256) ? sinf(ang) : cosf(ang);
}

__global__ __launch_bounds__(256) void add_temb_kernel(
    const float* __restrict__ xin, const float* __restrict__ temb,
    unsigned short* __restrict__ out)
{
    const size_t i4 = (size_t)blockIdx.x * 256 + threadIdx.x;
    const size_t elem = i4 * 4;
    const int b = (int)(elem >> 18);
    const int c = (int)(elem & (CHN - 1));
    const float4 a = reinterpret_cast<const float4*>(xin)[i4];
    const float4 tv = *reinterpret_cast<const float4*>(temb + (size_t)b * CHN + c);
    ushort4 o;
    o.x = f2b(a.x + tv.x); o.y = f2b(a.y + tv.y);
    o.z = f2b(a.z + tv.z); o.w = f2b(a.w + tv.w);
    reinterpret_cast<ushort4*>(out)[i4] = o;
}

// ---------------------------------------------------------------------------
extern "C" void kernel_launch(void* const* d_in, const int* in_sizes, int n_in,
                              void* d_out, int out_size, void* d_ws, size_t ws_size,
                              hipStream_t stream)
{
    (void)in_sizes; (void)n_in; (void)out_size; (void)ws_size;
    const float* log_seqs = (const float*)d_in[0];
    const float* seqs_nxt = (const float*)d_in[1];
    const int*   tt       = (const int*)d_in[2];
    const float* qw  = (const float*)d_in[3];
    const float* qb  = (const float*)d_in[4];
    const float* kw  = (const float*)d_in[5];
    const float* kb  = (const float*)d_in[6];
    const float* vw  = (const float*)d_in[7];
    const float* vb  = (const float*)d_in[8];
    const float* ln1g = (const float*)d_in[9];
    const float* ln1b = (const float*)d_in[10];
    const float* ln2g = (const float*)d_in[11];
    const float* ln2b = (const float*)d_in[12];
    const float* c1w = (const float*)d_in[13];
    const float* c1b = (const float*)d_in[14];
    const float* c2w = (const float*)d_in[15];
    const float* c2b = (const float*)d_in[16];
    const float* posK = (const float*)d_in[17];
    const float* posV = (const float*)d_in[18];
    const float* lng = (const float*)d_in[19];
    const float* lnb = (const float*)d_in[20];
    const float* tw0 = (const float*)d_in[21];
    const float* tb0 = (const float*)d_in[22];
    const float* tw1 = (const float*)d_in[23];
    const float* tb1 = (const float*)d_in[24];
    const float* tw2 = (const float*)d_in[25];
    const float* tb2 = (const float*)d_in[26];
    const float* decw = (const float*)d_in[27];
    const float* decb = (const float*)d_in[28];

    const size_t SZ = (size_t)BB * LL * CHN;  // 8388608
    const int M = BB * LL;                    // 16384
    float* out = (float*)d_out;
    float* log_feats = out;
    float* dec = out + SZ;
    unsigned short* QBb = (unsigned short*)dec;        // Q bf16 until decoder
    unsigned short* VTb = (unsigned short*)log_feats;  // V^T bf16 until final LN

    float* ws = (float*)d_ws;
    float* S = ws;                                            // SZ f32
    unsigned short* KBb = (unsigned short*)(ws + SZ);         // SZ bf16
    unsigned short* R0  = (unsigned short*)(ws + SZ + SZ / 2);
    unsigned short* R1  = (unsigned short*)(ws + 2 * SZ);
    unsigned short* WBu = (unsigned short*)(ws + 2 * SZ + SZ / 2);  // 3145728 bf16
    float* T0 = ws + 2 * SZ + SZ / 2 + 1572864;
    float* T1 = T0 + 32 * CHN;
    float* T2 = T1 + 32 * 2048;
    float* T3 = T2 + 32 * 2048;
    float* P  = S;   // split-K partials (S is dead after the final LN)

    const size_t WQ = 0, WK = 524288, WV = 1048576, WC1 = 1572864,
                 WC2 = 2097152, WDEC = 2621440;

    auto mg = [&](const unsigned short* A, const unsigned short* W, int ldw,
                  const float* bias, const float* pos, const float* res,
                  float* outf, unsigned short* outb, unsigned short* outbt, int act) {
        mgemm_kernel<<<512, 256, 0, stream>>>(A, W, ldw, bias, pos, res,
                                              outf, outb, outbt, act);
    };
    auto skg = [&](const float* A, int K, const float* W, int N,
                   const float* bias, float* o, int act) {
        skgemm_kernel<<<dim3(N / 256, K / 128), 256, 0, stream>>>(A, K, W, N, P);
        skreduce_kernel<<<(N * 32) / 256, 256, 0, stream>>>(P, K / 128, bias, o, N, act);
    };

    // weight + input conversions (one fat launch + one big cvt)
    cvt6_kernel<<<dim3(512, 6), 256, 0, stream>>>(qw, kw, vw, c1w, c2w, decw, WBu);
    cvt_kernel<<<(int)(SZ / 4 / 256), 256, 0, stream>>>(log_seqs, R1, (int)(SZ / 4));

    const float* cur = log_seqs;
    for (int i = 0; i < 2; ++i) {
        const size_t wo = (size_t)i * 262144;
        const size_t bo = (size_t)i * CHN;
        unsigned short* qinb = (i == 0) ? R0 : R1;
        unsigned short* curb = (i == 0) ? R1 : R0;
        unsigned short* smb  = qinb;
        unsigned short* hb   = curb;
        unsigned short* ncb  = (i == 0) ? qinb : nullptr;

        ln_kernel<<<M, 256, 0, stream>>>(cur, ln1g + bo, ln1b + bo, nullptr, qinb);
        qkv_kernel<<<dim3(512, 3), 256, 0, stream>>>(
            qinb, curb, WBu + WQ + wo, WBu + WK + wo, WBu + WV + wo,
            qb + bo, kb + bo, vb + bo, posK, posV, QBb, KBb, VTb);
        mattn_kernel<<<dim3(LL / 64, NHH, BB), 256, 0, stream>>>(QBb, KBb, VTb, qinb, S);
        ln_kernel<<<M, 256, 0, stream>>>(S, ln2g + bo, ln2b + bo, S, smb);
        mg(smb, WBu + WC1 + wo, 512, c1b + bo, nullptr, nullptr, nullptr, hb, nullptr, 1);
        mg(hb, WBu + WC2 + wo, 512, c2b + bo, nullptr, S, S, ncb, nullptr, 0);
        cur = S;
    }

    ln_kernel<<<M, 256, 0, stream>>>(S, lng, lnb, log_feats, R0);

    temb_embed_kernel<<<(BB * CHN) / 256, 256, 0, stream>>>(tt, T0);
    skg(T0, 512, tw0, 2048, tb0, T1, 2);
    skg(T1, 2048, tw1, 2048, tb1, T2, 2);
    skg(T2, 2048, tw2, 512, tb2, T3, 0);
    add_temb_kernel<<<(M * CHN / 4) / 256, 256, 0, stream>>>(seqs_nxt, T3, R1);

    dec_kernel<<<512, 256, 0, stream>>>(R0, R1, WBu + WDEC, decb, dec);
}

// Round 8
// 693.865 us; speedup vs baseline: 3.3857x; 1.1023x over previous
//
#include <hip/hip_runtime.h>
#include <math.h>

#define BB 32
#define LL 512
#define CHN 512
#define NHH 8
#define HDD 64

typedef __attribute__((ext_vector_type(8))) short short8;
typedef __attribute__((ext_vector_type(4))) float f32x4;

__device__ __forceinline__ float b2f(unsigned short s) {
    union { unsigned int u; float f; } c; c.u = ((unsigned int)s) << 16; return c.f;
}
__device__ __forceinline__ unsigned short f2b(float f) {
    union { float f; unsigned int u; } c; c.f = f;
    return (unsigned short)((c.u + 0x7fffu + ((c.u >> 16) & 1u)) >> 16);
}

// swizzled ushort index for a [rows][64] bf16 LDS tile (breaks 128B-stride conflicts)
#define SWZ(row, col) ((((row) * 64 + (col))) ^ (((row) & 7) << 3))

__device__ __forceinline__ void gl16(const unsigned short* g, unsigned short* l) {
    __builtin_amdgcn_global_load_lds(
        (const __attribute__((address_space(1))) unsigned int*)g,
        (__attribute__((address_space(3))) unsigned int*)l, 16, 0, 0);
}

// ---------------------------------------------------------------------------
// f32 -> bf16 bulk converts
// ---------------------------------------------------------------------------
__global__ __launch_bounds__(256) void cvt_kernel(
    const float* __restrict__ x, unsigned short* __restrict__ y, int n4)
{
    int i = blockIdx.x * 256 + threadIdx.x;
    if (i >= n4) return;
    const float4 v = reinterpret_cast<const float4*>(x)[i];
    ushort4 o;
    o.x = f2b(v.x); o.y = f2b(v.y); o.z = f2b(v.z); o.w = f2b(v.w);
    reinterpret_cast<ushort4*>(y)[i] = o;
}

// 6 weight matrices (512x512 f32 each) -> contiguous bf16 slab
__global__ __launch_bounds__(256) void cvt6_kernel(
    const float* __restrict__ p0, const float* __restrict__ p1,
    const float* __restrict__ p2, const float* __restrict__ p3,
    const float* __restrict__ p4, const float* __restrict__ p5,
    unsigned short* __restrict__ y)
{
    const int j = blockIdx.y;
    const float* x = j == 0 ? p0 : j == 1 ? p1 : j == 2 ? p2
                   : j == 3 ? p3 : j == 4 ? p4 : p5;
    const int i = blockIdx.x * 256 + threadIdx.x;   // 0..131071 float4s
    const float4 v = reinterpret_cast<const float4*>(x)[i];
    ushort4 o;
    o.x = f2b(v.x); o.y = f2b(v.y); o.z = f2b(v.z); o.w = f2b(v.w);
    reinterpret_cast<ushort4*>(y + (size_t)j * 524288)[i] = o;
}

// ---------------------------------------------------------------------------
// Row LayerNorm over CH=512 (eps=1e-8). Optional f32 and/or bf16 outputs.
// ---------------------------------------------------------------------------
__global__ __launch_bounds__(256) void ln_kernel(
    const float* __restrict__ x, const float* __restrict__ g,
    const float* __restrict__ b, float* __restrict__ yf,
    unsigned short* __restrict__ yb)
{
    const int row = blockIdx.x;
    const int tid = threadIdx.x;
    const size_t base = (size_t)row * CHN;
    float2 v = *reinterpret_cast<const float2*>(x + base + tid * 2);
    float s  = v.x + v.y;
    float ss = v.x * v.x + v.y * v.y;
    #pragma unroll
    for (int m = 1; m < 64; m <<= 1) {
        s  += __shfl_xor(s, m);
        ss += __shfl_xor(ss, m);
    }
    __shared__ float red[8];
    const int wave = tid >> 6;
    if ((tid & 63) == 0) { red[wave] = s; red[4 + wave] = ss; }
    __syncthreads();
    s  = red[0] + red[1] + red[2] + red[3];
    ss = red[4] + red[5] + red[6] + red[7];
    const float mean = s * (1.0f / CHN);
    const float var  = ss * (1.0f / CHN) - mean * mean;
    const float inv  = rsqrtf(var + 1e-8f);
    const int c = tid * 2;
    float2 o;
    o.x = (v.x - mean) * inv * g[c]     + b[c];
    o.y = (v.y - mean) * inv * g[c + 1] + b[c + 1];
    if (yf) *reinterpret_cast<float2*>(yf + base + c) = o;
    if (yb) {
        ushort2 ob; ob.x = f2b(o.x); ob.y = f2b(o.y);
        *reinterpret_cast<ushort2*>(yb + base + c) = ob;
    }
}

// ---------------------------------------------------------------------------
// bf16 MFMA GEMM body: 128x128 tile, BK=32, 4 waves, depth-3 counted-vmcnt
// pipeline (T3/T4). NT = K/32 steps; A2 != null supplies k >= 512 (dec).
// outbt: transposed bf16 write VT[(row>>9)*512 + col][row&511] as ushort4.
// ---------------------------------------------------------------------------
template <int NT>
__device__ __forceinline__ void gemm_body(
    const unsigned short* __restrict__ A,
    const unsigned short* __restrict__ A2,
    const unsigned short* __restrict__ W, int ldw,
    const float* __restrict__ bias,
    const float* __restrict__ pos,
    const float* __restrict__ res,
    float* __restrict__ outf,
    unsigned short* __restrict__ outb,
    unsigned short* __restrict__ outbt,
    int act, int bid)
{
    __shared__ alignas(16) unsigned short lA[3][4096];
    __shared__ alignas(16) unsigned short lB[3][4096];

    const int tid  = threadIdx.x;
    const int lane = tid & 63;
    const int wid  = tid >> 6;

    const int swz = (bid & 7) * 64 + (bid >> 3);
    const int by = swz >> 2, bx = swz & 3;
    const int bm = by * 128, bn = bx * 128;

    const unsigned short* Ax = A2 ? A2 : A;
    const unsigned short* aS0  = A  + (size_t)(bm + lane) * 512 + wid * 8;
    const unsigned short* aS1  = A  + (size_t)(bm + 64 + lane) * 512 + wid * 8;
    const unsigned short* a2S0 = Ax + (size_t)(bm + lane) * 512 + wid * 8;
    const unsigned short* a2S1 = Ax + (size_t)(bm + 64 + lane) * 512 + wid * 8;
    const unsigned short* wS0  = W + (size_t)(bn + lane) * ldw + wid * 8;
    const unsigned short* wS1  = W + (size_t)(bn + 64 + lane) * ldw + wid * 8;

    const int wr = wid >> 1, wc = wid & 1;
    const int fr = lane & 15;
    const int fq = lane >> 4;

    f32x4 acc[4][4];
    #pragma unroll
    for (int m = 0; m < 4; ++m)
        #pragma unroll
        for (int n = 0; n < 4; ++n)
            acc[m][n] = (f32x4){0.f, 0.f, 0.f, 0.f};

    #define MG_STAGE(buf, t)                                            \
        do {                                                            \
            const int k0 = ((t) & 15) * 32;                             \
            const unsigned short* s0 = ((t) < 16) ? aS0 : a2S0;         \
            const unsigned short* s1 = ((t) < 16) ? aS1 : a2S1;         \
            gl16(s0 + k0, &lA[buf][wid * 1024]);                        \
            gl16(s1 + k0, &lA[buf][wid * 1024 + 512]);                  \
            gl16(wS0 + (t) * 32, &lB[buf][wid * 1024]);                 \
            gl16(wS1 + (t) * 32, &lB[buf][wid * 1024 + 512]);           \
        } while (0)

    MG_STAGE(0, 0);
    MG_STAGE(1, 1);

    #pragma unroll
    for (int t = 0; t < NT; ++t) {
        const int cur = t % 3;
        if (t + 2 < NT) {
            MG_STAGE((t + 2) % 3, t + 2);
            asm volatile("s_waitcnt vmcnt(8)" ::: "memory");
        } else if (t + 1 < NT) {
            asm volatile("s_waitcnt vmcnt(4)" ::: "memory");
        } else {
            asm volatile("s_waitcnt vmcnt(0)" ::: "memory");
        }
        __builtin_amdgcn_s_barrier();

        const unsigned short* pa = &lA[cur][(fq * 128 + wr * 64 + fr) * 8];
        const unsigned short* pb = &lB[cur][(fq * 128 + wc * 64 + fr) * 8];
        short8 aF[4], bF[4];
        #pragma unroll
        for (int m = 0; m < 4; ++m)
            aF[m] = *reinterpret_cast<const short8*>(pa + m * 128);
        #pragma unroll
        for (int n = 0; n < 4; ++n)
            bF[n] = *reinterpret_cast<const short8*>(pb + n * 128);
        asm volatile("s_waitcnt lgkmcnt(0)" ::: "memory");
        __builtin_amdgcn_s_barrier();

        __builtin_amdgcn_s_setprio(1);
        #pragma unroll
        for (int m = 0; m < 4; ++m)
            #pragma unroll
            for (int n = 0; n < 4; ++n)
                acc[m][n] = __builtin_amdgcn_mfma_f32_16x16x32_bf16(
                    aF[m], bF[n], acc[m][n], 0, 0, 0);
        __builtin_amdgcn_s_setprio(0);
    }
    #undef MG_STAGE

    const int row0 = bm + wr * 64, col0 = bn + wc * 64;
    #pragma unroll
    for (int m = 0; m < 4; ++m) {
        #pragma unroll
        for (int n = 0; n < 4; ++n) {
            const int col = col0 + n * 16 + fr;
            const float bia = bias ? bias[col] : 0.f;
            ushort4 o4;
            #pragma unroll
            for (int r = 0; r < 4; ++r) {
                const int row = row0 + m * 16 + fq * 4 + r;
                float v = acc[m][n][r] + bia;
                if (pos) v += pos[(size_t)(row & (LL - 1)) * CHN + col];
                if (act == 1) v = fmaxf(v, 0.f);
                const size_t idx = (size_t)row * CHN + col;
                if (res) v += res[idx];
                if (outf) outf[idx] = v;
                if (outb) outb[idx] = f2b(v);
                ((unsigned short*)&o4)[r] = f2b(v);
            }
            if (outbt) {
                const int rw = row0 + m * 16 + fq * 4;   // 4-aligned, no 512-cross
                *reinterpret_cast<ushort4*>(
                    &outbt[((size_t)(rw >> 9) * 512 + col) * 512 + (rw & 511)]) = o4;
            }
        }
    }
}

__global__ __launch_bounds__(256) void mgemm_kernel(
    const unsigned short* __restrict__ A,
    const unsigned short* __restrict__ W, int ldw,
    const float* __restrict__ bias,
    const float* __restrict__ pos,
    const float* __restrict__ res,
    float* __restrict__ outf,
    unsigned short* __restrict__ outb,
    unsigned short* __restrict__ outbt,
    int act)
{
    gemm_body<16>(A, nullptr, W, ldw, bias, pos, res, outf, outb, outbt, act,
                  blockIdx.x);
}

// Q/K/V fused: blockIdx.y selects job (0=Q, 1=K, 2=V^T)
__global__ __launch_bounds__(256) void qkv_kernel(
    const unsigned short* __restrict__ qinb, const unsigned short* __restrict__ curb,
    const unsigned short* __restrict__ Wq, const unsigned short* __restrict__ Wk,
    const unsigned short* __restrict__ Wv,
    const float* __restrict__ qb, const float* __restrict__ kb,
    const float* __restrict__ vb,
    const float* __restrict__ posK, const float* __restrict__ posV,
    unsigned short* __restrict__ QBb, unsigned short* __restrict__ KBb,
    unsigned short* __restrict__ VTb)
{
    const int job = blockIdx.y;
    const unsigned short* A = (job == 0) ? qinb : curb;
    const unsigned short* W = (job == 0) ? Wq : (job == 1) ? Wk : Wv;
    const float* bias = (job == 0) ? qb : (job == 1) ? kb : vb;
    const float* pos  = (job == 0) ? nullptr : (job == 1) ? posK : posV;
    unsigned short* outb  = (job == 0) ? QBb : (job == 1) ? KBb : nullptr;
    unsigned short* outbt = (job == 2) ? VTb : nullptr;
    gemm_body<16>(A, nullptr, W, 512, bias, pos, nullptr, nullptr, outb, outbt, 0,
                  blockIdx.x);
}

// Decoder fused: dec = [log_feats | x_t] @ decw^T + decb  (K=1024, two A sources)
__global__ __launch_bounds__(256) void dec_kernel(
    const unsigned short* __restrict__ R0b, const unsigned short* __restrict__ R1b,
    const unsigned short* __restrict__ Wd, const float* __restrict__ decb,
    float* __restrict__ dec)
{
    gemm_body<32>(R0b, R1b, Wd, 1024, decb, nullptr, nullptr, dec, nullptr, nullptr,
                  0, blockIdx.x);
}

// ---------------------------------------------------------------------------
// Split-K small-M GEMM for the temb path.
// ---------------------------------------------------------------------------
__global__ __launch_bounds__(256) void skgemm_kernel(
    const float* __restrict__ A, int K,
    const float* __restrict__ W, int N,
    float* __restrict__ P)
{
    __shared__ float As[32][128];
    const int tid = threadIdx.x;
    const int kz  = blockIdx.y;
    const int c   = blockIdx.x * 256 + tid;

    #pragma unroll
    for (int i = 0; i < 16; ++i) {
        const int idx = i * 256 + tid;
        const int r = idx >> 7, k = idx & 127;
        As[r][k] = A[(size_t)r * K + kz * 128 + k];
    }
    __syncthreads();

    float acc[32];
    #pragma unroll
    for (int r = 0; r < 32; ++r) acc[r] = 0.f;

    const float* wrow = W + (size_t)c * K + kz * 128;
    for (int k4 = 0; k4 < 32; ++k4) {
        const float4 w = reinterpret_cast<const float4*>(wrow)[k4];
        #pragma unroll
        for (int r = 0; r < 32; ++r) {
            const float4 a = *reinterpret_cast<const float4*>(&As[r][k4 * 4]);
            acc[r] = fmaf(w.x, a.x, fmaf(w.y, a.y, fmaf(w.z, a.z, fmaf(w.w, a.w, acc[r]))));
        }
    }

    float* pp = P + ((size_t)kz * N + c) * 32;
    #pragma unroll
    for (int r = 0; r < 32; ++r) pp[r] = acc[r];
}

__global__ __launch_bounds__(256) void skreduce_kernel(
    const float* __restrict__ P, int KS, const float* __restrict__ bias,
    float* __restrict__ out, int N, int act)
{
    const int idx = blockIdx.x * 256 + threadIdx.x;
    const int r = idx & 31, c = idx >> 5;
    float s = 0.f;
    for (int kz = 0; kz < KS; ++kz)
        s += P[(size_t)kz * N * 32 + idx];
    s += bias[c];
    if (act == 2) s = s / (1.f + __expf(-s));
    out[(size_t)r * N + c] = s;
}

// ---------------------------------------------------------------------------
// MFMA causal flash attention (round-6 numeric path + T5 setprio).
// ---------------------------------------------------------------------------
__global__ __launch_bounds__(256) void mattn_kernel(
    const unsigned short* __restrict__ Q, const unsigned short* __restrict__ K,
    const unsigned short* __restrict__ VT, const unsigned short* __restrict__ Qin,
    float* __restrict__ Sout)
{
    __shared__ alignas(16) unsigned short kT[2][4096];
    __shared__ alignas(16) unsigned short vT[2][4096];
    __shared__ unsigned short pl[4][1024];

    const int qt = blockIdx.x;
    const int h  = blockIdx.y;
    const int b  = blockIdx.z;
    const int tid = threadIdx.x, lane = tid & 63, wid = tid >> 6;
    const int fr = lane & 15, fq = lane >> 4;
    const int hc = h * HDD;

    const int c0i = tid, c1i = 256 + tid;
    const int r0s = c0i >> 3, j0s = c0i & 7, d0s = ((j0s ^ (r0s & 7)) << 3);
    const int r1s = c1i >> 3, j1s = c1i & 7, d1s = ((j1s ^ (r1s & 7)) << 3);
    const unsigned short* kS0 = K + (size_t)b * LL * CHN + (size_t)r0s * CHN + hc + d0s;
    const unsigned short* kS1 = K + (size_t)b * LL * CHN + (size_t)r1s * CHN + hc + d1s;
    const unsigned short* vS0 = VT + ((size_t)(b * NHH + h) * 64 + r0s) * 512 + d0s;
    const unsigned short* vS1 = VT + ((size_t)(b * NHH + h) * 64 + r1s) * 512 + d1s;

    #define AT_STAGE(buf, ch)                                              \
        do {                                                               \
            const int o = (ch) * 64;                                       \
            gl16(kS0 + (size_t)o * CHN, &kT[buf][wid * 512]);              \
            gl16(kS1 + (size_t)o * CHN, &kT[buf][2048 + wid * 512]);       \
            gl16(vS0 + o, &vT[buf][wid * 512]);                            \
            gl16(vS1 + o, &vT[buf][2048 + wid * 512]);                     \
        } while (0)

    const size_t qrow = (size_t)b * LL + qt * 64 + wid * 16 + fr;
    short8 qf[2];
    qf[0] = *reinterpret_cast<const short8*>(Q + qrow * CHN + hc + fq * 8);
    qf[1] = *reinterpret_cast<const short8*>(Q + qrow * CHN + hc + 32 + fq * 8);

    f32x4 oacc[4];
    #pragma unroll
    for (int n = 0; n < 4; ++n) oacc[n] = (f32x4){0.f, 0.f, 0.f, 0.f};
    float mrow[4], lrow[4];
    #pragma unroll
    for (int r = 0; r < 4; ++r) { mrow[r] = -1e30f; lrow[r] = 0.f; }

    AT_STAGE(0, 0);
    __syncthreads();

    for (int ch = 0; ch <= qt; ++ch) {
        const int cur = ch & 1;
        if (ch < qt) AT_STAGE(cur ^ 1, ch + 1);

        f32x4 sacc[4];
        #pragma unroll
        for (int n = 0; n < 4; ++n) sacc[n] = (f32x4){0.f, 0.f, 0.f, 0.f};
        __builtin_amdgcn_s_setprio(1);
        #pragma unroll
        for (int kk = 0; kk < 2; ++kk) {
            #pragma unroll
            for (int n = 0; n < 4; ++n) {
                const short8 kf = *reinterpret_cast<const short8*>(
                    &kT[cur][SWZ(n * 16 + fr, kk * 32 + fq * 8)]);
                sacc[n] = __builtin_amdgcn_mfma_f32_16x16x32_bf16(qf[kk], kf, sacc[n], 0, 0, 0);
            }
        }
        __builtin_amdgcn_s_setprio(0);

        const bool diag = (ch == qt);
        #pragma unroll
        for (int r = 0; r < 4; ++r) {
            float sv[4];
            #pragma unroll
            for (int n = 0; n < 4; ++n) {
                float v = sacc[n][r] * 0.125f;
                if (diag && (n * 16 + fr > wid * 16 + fq * 4 + r)) v = -1e30f;
                sv[n] = v;
            }
            float cm = fmaxf(fmaxf(sv[0], sv[1]), fmaxf(sv[2], sv[3]));
            cm = fmaxf(cm, __shfl_xor(cm, 1));
            cm = fmaxf(cm, __shfl_xor(cm, 2));
            cm = fmaxf(cm, __shfl_xor(cm, 4));
            cm = fmaxf(cm, __shfl_xor(cm, 8));
            const float mn = fmaxf(mrow[r], cm);
            const float f = __expf(mrow[r] - mn);
            mrow[r] = mn;
            float ps = 0.f;
            #pragma unroll
            for (int n = 0; n < 4; ++n) { sv[n] = __expf(sv[n] - mn); ps += sv[n]; }
            ps += __shfl_xor(ps, 1);
            ps += __shfl_xor(ps, 2);
            ps += __shfl_xor(ps, 4);
            ps += __shfl_xor(ps, 8);
            lrow[r] = lrow[r] * f + ps;
            #pragma unroll
            for (int n = 0; n < 4; ++n) {
                oacc[n][r] *= f;
                pl[wid][SWZ(fq * 4 + r, n * 16 + fr)] = f2b(sv[n]);
            }
        }

        __builtin_amdgcn_s_setprio(1);
        #pragma unroll
        for (int kk = 0; kk < 2; ++kk) {
            const short8 pa = *reinterpret_cast<const short8*>(
                &pl[wid][SWZ(fr, kk * 32 + fq * 8)]);
            #pragma unroll
            for (int n = 0; n < 4; ++n) {
                const short8 vf = *reinterpret_cast<const short8*>(
                    &vT[cur][SWZ(n * 16 + fr, kk * 32 + fq * 8)]);
                oacc[n] = __builtin_amdgcn_mfma_f32_16x16x32_bf16(pa, vf, oacc[n], 0, 0, 0);
            }
        }
        __builtin_amdgcn_s_setprio(0);
        __syncthreads();
    }
    #undef AT_STAGE

    const size_t orow0 = (size_t)b * LL + qt * 64 + wid * 16 + fq * 4;
    #pragma unroll
    for (int r = 0; r < 4; ++r) {
        const float inv = 1.f / lrow[r];
        const size_t rowidx = (orow0 + r) * CHN + hc;
        #pragma unroll
        for (int n = 0; n < 4; ++n) {
            const int d = n * 16 + fr;
            Sout[rowidx + d] = oacc[n][r] * inv + b2f(Qin[rowidx + d]);
        }
    }
}

// ---------------------------------------------------------------------------
__global__ __launch_bounds__(256) void temb_embed_kernel(
    const int* __restrict__ t, float* __restrict__ T0)
{
    const int idx = blockIdx.x * 256 + threadIdx.x;
    const int b = idx >> 9, j = idx & 511;
    const float tv = (float)t[b];
    const int jj = (j < 256) ? j : j - 256;
    const float freq = __expf((float)jj * (-9.210340371976184f / 255.f));
    const float ang = tv * freq;
    T0[idx] = (j < 256) ? sinf(ang) : cosf(ang);
}

__global__ __launch_bounds__(256) void add_temb_kernel(
    const float* __restrict__ xin, const float* __restrict__ temb,
    unsigned short* __restrict__ out)
{
    const size_t i4 = (size_t)blockIdx.x * 256 + threadIdx.x;
    const size_t elem = i4 * 4;
    const int b = (int)(elem >> 18);
    const int c = (int)(elem & (CHN - 1));
    const float4 a = reinterpret_cast<const float4*>(xin)[i4];
    const float4 tv = *reinterpret_cast<const float4*>(temb + (size_t)b * CHN + c);
    ushort4 o;
    o.x = f2b(a.x + tv.x); o.y = f2b(a.y + tv.y);
    o.z = f2b(a.z + tv.z); o.w = f2b(a.w + tv.w);
    reinterpret_cast<ushort4*>(out)[i4] = o;
}

// ---------------------------------------------------------------------------
extern "C" void kernel_launch(void* const* d_in, const int* in_sizes, int n_in,
                              void* d_out, int out_size, void* d_ws, size_t ws_size,
                              hipStream_t stream)
{
    (void)in_sizes; (void)n_in; (void)out_size; (void)ws_size;
    const float* log_seqs = (const float*)d_in[0];
    const float* seqs_nxt = (const float*)d_in[1];
    const int*   tt       = (const int*)d_in[2];
    const float* qw  = (const float*)d_in[3];
    const float* qb  = (const float*)d_in[4];
    const float* kw  = (const float*)d_in[5];
    const float* kb  = (const float*)d_in[6];
    const float* vw  = (const float*)d_in[7];
    const float* vb  = (const float*)d_in[8];
    const float* ln1g = (const float*)d_in[9];
    const float* ln1b = (const float*)d_in[10];
    const float* ln2g = (const float*)d_in[11];
    const float* ln2b = (const float*)d_in[12];
    const float* c1w = (const float*)d_in[13];
    const float* c1b = (const float*)d_in[14];
    const float* c2w = (const float*)d_in[15];
    const float* c2b = (const float*)d_in[16];
    const float* posK = (const float*)d_in[17];
    const float* posV = (const float*)d_in[18];
    const float* lng = (const float*)d_in[19];
    const float* lnb = (const float*)d_in[20];
    const float* tw0 = (const float*)d_in[21];
    const float* tb0 = (const float*)d_in[22];
    const float* tw1 = (const float*)d_in[23];
    const float* tb1 = (const float*)d_in[24];
    const float* tw2 = (const float*)d_in[25];
    const float* tb2 = (const float*)d_in[26];
    const float* decw = (const float*)d_in[27];
    const float* decb = (const float*)d_in[28];

    const size_t SZ = (size_t)BB * LL * CHN;  // 8388608
    const int M = BB * LL;                    // 16384
    float* out = (float*)d_out;
    float* log_feats = out;
    float* dec = out + SZ;
    unsigned short* QBb = (unsigned short*)dec;        // Q bf16 until decoder
    unsigned short* VTb = (unsigned short*)log_feats;  // V^T bf16 until final LN

    float* ws = (float*)d_ws;
    float* S = ws;                                            // SZ f32
    unsigned short* KBb = (unsigned short*)(ws + SZ);         // SZ bf16
    unsigned short* R0  = (unsigned short*)(ws + SZ + SZ / 2);
    unsigned short* R1  = (unsigned short*)(ws + 2 * SZ);
    unsigned short* WBu = (unsigned short*)(ws + 2 * SZ + SZ / 2);  // 3145728 bf16
    float* T0 = ws + 2 * SZ + SZ / 2 + 1572864;
    float* T1 = T0 + 32 * CHN;
    float* T2 = T1 + 32 * 2048;
    float* T3 = T2 + 32 * 2048;
    float* P  = S;   // split-K partials (S is dead after the final LN)

    const size_t WQ = 0, WK = 524288, WV = 1048576, WC1 = 1572864,
                 WC2 = 2097152, WDEC = 2621440;

    auto mg = [&](const unsigned short* A, const unsigned short* W, int ldw,
                  const float* bias, const float* pos, const float* res,
                  float* outf, unsigned short* outb, unsigned short* outbt, int act) {
        mgemm_kernel<<<512, 256, 0, stream>>>(A, W, ldw, bias, pos, res,
                                              outf, outb, outbt, act);
    };
    auto skg = [&](const float* A, int K, const float* W, int N,
                   const float* bias, float* o, int act) {
        skgemm_kernel<<<dim3(N / 256, K / 128), 256, 0, stream>>>(A, K, W, N, P);
        skreduce_kernel<<<(N * 32) / 256, 256, 0, stream>>>(P, K / 128, bias, o, N, act);
    };

    // weight + input conversions (one fat launch + one big cvt)
    cvt6_kernel<<<dim3(512, 6), 256, 0, stream>>>(qw, kw, vw, c1w, c2w, decw, WBu);
    cvt_kernel<<<(int)(SZ / 4 / 256), 256, 0, stream>>>(log_seqs, R1, (int)(SZ / 4));

    const float* cur = log_seqs;
    for (int i = 0; i < 2; ++i) {
        const size_t wo = (size_t)i * 262144;
        const size_t bo = (size_t)i * CHN;
        unsigned short* qinb = (i == 0) ? R0 : R1;
        unsigned short* curb = (i == 0) ? R1 : R0;
        unsigned short* smb  = qinb;
        unsigned short* hb   = curb;
        unsigned short* ncb  = (i == 0) ? qinb : nullptr;

        ln_kernel<<<M, 256, 0, stream>>>(cur, ln1g + bo, ln1b + bo, nullptr, qinb);
        qkv_kernel<<<dim3(512, 3), 256, 0, stream>>>(
            qinb, curb, WBu + WQ + wo, WBu + WK + wo, WBu + WV + wo,
            qb + bo, kb + bo, vb + bo, posK, posV, QBb, KBb, VTb);
        mattn_kernel<<<dim3(LL / 64, NHH, BB), 256, 0, stream>>>(QBb, KBb, VTb, qinb, S);
        ln_kernel<<<M, 256, 0, stream>>>(S, ln2g + bo, ln2b + bo, S, smb);
        mg(smb, WBu + WC1 + wo, 512, c1b + bo, nullptr, nullptr, nullptr, hb, nullptr, 1);
        mg(hb, WBu + WC2 + wo, 512, c2b + bo, nullptr, S, S, ncb, nullptr, 0);
        cur = S;
    }

    ln_kernel<<<M, 256, 0, stream>>>(S, lng, lnb, log_feats, R0);

    temb_embed_kernel<<<(BB * CHN) / 256, 256, 0, stream>>>(tt, T0);
    skg(T0, 512, tw0, 2048, tb0, T1, 2);
    skg(T1, 2048, tw1, 2048, tb1, T2, 2);
    skg(T2, 2048, tw2, 512, tb2, T3, 0);
    add_temb_kernel<<<(M * CHN / 4) / 256, 256, 0, stream>>>(seqs_nxt, T3, R1);

    dec_kernel<<<512, 256, 0, stream>>>(R0, R1, WBu + WDEC, decb, dec);
}

// Round 9
// 678.036 us; speedup vs baseline: 3.4647x; 1.0233x over previous
//
#include <hip/hip_runtime.h>
#include <math.h>

#define BB 32
#define LL 512
#define CHN 512
#define NHH 8
#define HDD 64

typedef __attribute__((ext_vector_type(8))) short short8;
typedef __attribute__((ext_vector_type(4))) float f32x4;

__device__ __forceinline__ float b2f(unsigned short s) {
    union { unsigned int u; float f; } c; c.u = ((unsigned int)s) << 16; return c.f;
}
__device__ __forceinline__ unsigned short f2b(float f) {
    union { float f; unsigned int u; } c; c.f = f;
    return (unsigned short)((c.u + 0x7fffu + ((c.u >> 16) & 1u)) >> 16);
}

// swizzled ushort index for a [rows][64] bf16 LDS tile (breaks 128B-stride conflicts)
#define SWZ(row, col) ((((row) * 64 + (col))) ^ (((row) & 7) << 3))

__device__ __forceinline__ void gl16(const unsigned short* g, unsigned short* l) {
    __builtin_amdgcn_global_load_lds(
        (const __attribute__((address_space(1))) unsigned int*)g,
        (__attribute__((address_space(3))) unsigned int*)l, 16, 0, 0);
}

// ---------------------------------------------------------------------------
// f32 -> bf16 bulk converts
// ---------------------------------------------------------------------------
__global__ __launch_bounds__(256) void cvt_kernel(
    const float* __restrict__ x, unsigned short* __restrict__ y, int n4)
{
    int i = blockIdx.x * 256 + threadIdx.x;
    if (i >= n4) return;
    const float4 v = reinterpret_cast<const float4*>(x)[i];
    ushort4 o;
    o.x = f2b(v.x); o.y = f2b(v.y); o.z = f2b(v.z); o.w = f2b(v.w);
    reinterpret_cast<ushort4*>(y)[i] = o;
}

// 6 weight matrices (512x512 f32 each) -> contiguous bf16 slab
__global__ __launch_bounds__(256) void cvt6_kernel(
    const float* __restrict__ p0, const float* __restrict__ p1,
    const float* __restrict__ p2, const float* __restrict__ p3,
    const float* __restrict__ p4, const float* __restrict__ p5,
    unsigned short* __restrict__ y)
{
    const int j = blockIdx.y;
    const float* x = j == 0 ? p0 : j == 1 ? p1 : j == 2 ? p2
                   : j == 3 ? p3 : j == 4 ? p4 : p5;
    const int i = blockIdx.x * 256 + threadIdx.x;   // 0..131071 float4s
    const float4 v = reinterpret_cast<const float4*>(x)[i];
    ushort4 o;
    o.x = f2b(v.x); o.y = f2b(v.y); o.z = f2b(v.z); o.w = f2b(v.w);
    reinterpret_cast<ushort4*>(y + (size_t)j * 524288)[i] = o;
}

// ---------------------------------------------------------------------------
// Row LayerNorm over CH=512 (eps=1e-8). Optional f32 and/or bf16 outputs.
// ---------------------------------------------------------------------------
__global__ __launch_bounds__(256) void ln_kernel(
    const float* __restrict__ x, const float* __restrict__ g,
    const float* __restrict__ b, float* __restrict__ yf,
    unsigned short* __restrict__ yb)
{
    const int row = blockIdx.x;
    const int tid = threadIdx.x;
    const size_t base = (size_t)row * CHN;
    float2 v = *reinterpret_cast<const float2*>(x + base + tid * 2);
    float s  = v.x + v.y;
    float ss = v.x * v.x + v.y * v.y;
    #pragma unroll
    for (int m = 1; m < 64; m <<= 1) {
        s  += __shfl_xor(s, m);
        ss += __shfl_xor(ss, m);
    }
    __shared__ float red[8];
    const int wave = tid >> 6;
    if ((tid & 63) == 0) { red[wave] = s; red[4 + wave] = ss; }
    __syncthreads();
    s  = red[0] + red[1] + red[2] + red[3];
    ss = red[4] + red[5] + red[6] + red[7];
    const float mean = s * (1.0f / CHN);
    const float var  = ss * (1.0f / CHN) - mean * mean;
    const float inv  = rsqrtf(var + 1e-8f);
    const int c = tid * 2;
    float2 o;
    o.x = (v.x - mean) * inv * g[c]     + b[c];
    o.y = (v.y - mean) * inv * g[c + 1] + b[c + 1];
    if (yf) *reinterpret_cast<float2*>(yf + base + c) = o;
    if (yb) {
        ushort2 ob; ob.x = f2b(o.x); ob.y = f2b(o.y);
        *reinterpret_cast<ushort2*>(yb + base + c) = ob;
    }
}

// ---------------------------------------------------------------------------
// bf16 MFMA GEMM body: 256x128 tile, BK=32, 8 waves (4x2), depth-3
// counted-vmcnt pipeline. Per wave/step: 2 A-loads + 1 B-load (vmcnt 6/3/0),
// 8 ds_read_b128, 16 MFMA. NT = K/32; A2 != null supplies k >= 512 (dec).
// outbt: transposed bf16 write VT[(row>>9)*512 + col][row&511] as ushort4.
// ---------------------------------------------------------------------------
template <int NT>
__device__ __forceinline__ void gemm_body(
    const unsigned short* __restrict__ A,
    const unsigned short* __restrict__ A2,
    const unsigned short* __restrict__ W, int ldw,
    const float* __restrict__ bias,
    const float* __restrict__ pos,
    const float* __restrict__ res,
    float* __restrict__ outf,
    unsigned short* __restrict__ outb,
    unsigned short* __restrict__ outbt,
    int act, int bid)
{
    __shared__ alignas(16) unsigned short lA[3][8192];  // 256 rows x 32 k
    __shared__ alignas(16) unsigned short lB[3][4096];  // 128 rows x 32 k

    const int tid  = threadIdx.x;
    const int lane = tid & 63;
    const int wid  = tid >> 6;          // 0..7

    // XCD swizzle over 256 blocks (bijective: 256 % 8 == 0)
    const int swz = (bid & 7) * 32 + (bid >> 3);
    const int by = swz >> 2, bx = swz & 3;
    const int bm = by * 256, bn = bx * 128;

    // staging assignments
    const int ia0 = wid * 2, ia1 = wid * 2 + 1;        // A ops 0..15
    const int hiA0 = ia0 >> 2, rgA0 = ia0 & 3;
    const int hiA1 = ia1 >> 2, rgA1 = ia1 & 3;
    const int hiB = wid >> 1, rgB = wid & 1;           // B ops 0..7

    const unsigned short* Ax = A2 ? A2 : A;
    const unsigned short* aS0  = A  + (size_t)(bm + rgA0 * 64 + lane) * 512 + hiA0 * 8;
    const unsigned short* aS1  = A  + (size_t)(bm + rgA1 * 64 + lane) * 512 + hiA1 * 8;
    const unsigned short* a2S0 = Ax + (size_t)(bm + rgA0 * 64 + lane) * 512 + hiA0 * 8;
    const unsigned short* a2S1 = Ax + (size_t)(bm + rgA1 * 64 + lane) * 512 + hiA1 * 8;
    const unsigned short* wS   = W + (size_t)(bn + rgB * 64 + lane) * ldw + hiB * 8;
    const int dA0 = (hiA0 * 256 + rgA0 * 64) * 8;
    const int dA1 = (hiA1 * 256 + rgA1 * 64) * 8;
    const int dB  = (hiB * 128 + rgB * 64) * 8;

    const int wr = wid >> 1, wc = wid & 1;             // wave tile 64x64
    const int fr = lane & 15;
    const int fq = lane >> 4;

    f32x4 acc[4][4];
    #pragma unroll
    for (int m = 0; m < 4; ++m)
        #pragma unroll
        for (int n = 0; n < 4; ++n)
            acc[m][n] = (f32x4){0.f, 0.f, 0.f, 0.f};

    #define MG_STAGE(buf, t)                                            \
        do {                                                            \
            const int k0 = ((t) & 15) * 32;                             \
            const unsigned short* s0 = ((t) < 16) ? aS0 : a2S0;         \
            const unsigned short* s1 = ((t) < 16) ? aS1 : a2S1;         \
            gl16(s0 + k0, &lA[buf][dA0]);                               \
            gl16(s1 + k0, &lA[buf][dA1]);                               \
            gl16(wS + (t) * 32, &lB[buf][dB]);                          \
        } while (0)

    MG_STAGE(0, 0);
    MG_STAGE(1, 1);

    #pragma unroll
    for (int t = 0; t < NT; ++t) {
        const int cur = t % 3;
        if (t + 2 < NT) {
            MG_STAGE((t + 2) % 3, t + 2);
            asm volatile("s_waitcnt vmcnt(6)" ::: "memory");
        } else if (t + 1 < NT) {
            asm volatile("s_waitcnt vmcnt(3)" ::: "memory");
        } else {
            asm volatile("s_waitcnt vmcnt(0)" ::: "memory");
        }
        __builtin_amdgcn_s_barrier();

        const unsigned short* pa = &lA[cur][(fq * 256 + wr * 64 + fr) * 8];
        const unsigned short* pb = &lB[cur][(fq * 128 + wc * 64 + fr) * 8];
        short8 aF[4], bF[4];
        #pragma unroll
        for (int m = 0; m < 4; ++m)
            aF[m] = *reinterpret_cast<const short8*>(pa + m * 128);
        #pragma unroll
        for (int n = 0; n < 4; ++n)
            bF[n] = *reinterpret_cast<const short8*>(pb + n * 128);
        asm volatile("s_waitcnt lgkmcnt(0)" ::: "memory");
        __builtin_amdgcn_s_barrier();

        __builtin_amdgcn_s_setprio(1);
        #pragma unroll
        for (int m = 0; m < 4; ++m)
            #pragma unroll
            for (int n = 0; n < 4; ++n)
                acc[m][n] = __builtin_amdgcn_mfma_f32_16x16x32_bf16(
                    aF[m], bF[n], acc[m][n], 0, 0, 0);
        __builtin_amdgcn_s_setprio(0);
    }
    #undef MG_STAGE

    const int row0 = bm + wr * 64, col0 = bn + wc * 64;
    #pragma unroll
    for (int m = 0; m < 4; ++m) {
        #pragma unroll
        for (int n = 0; n < 4; ++n) {
            const int col = col0 + n * 16 + fr;
            const float bia = bias ? bias[col] : 0.f;
            ushort4 o4;
            #pragma unroll
            for (int r = 0; r < 4; ++r) {
                const int row = row0 + m * 16 + fq * 4 + r;
                float v = acc[m][n][r] + bia;
                if (pos) v += pos[(size_t)(row & (LL - 1)) * CHN + col];
                if (act == 1) v = fmaxf(v, 0.f);
                const size_t idx = (size_t)row * CHN + col;
                if (res) v += res[idx];
                if (outf) outf[idx] = v;
                if (outb) outb[idx] = f2b(v);
                ((unsigned short*)&o4)[r] = f2b(v);
            }
            if (outbt) {
                const int rw = row0 + m * 16 + fq * 4;   // 4-aligned, no 512-cross
                *reinterpret_cast<ushort4*>(
                    &outbt[((size_t)(rw >> 9) * 512 + col) * 512 + (rw & 511)]) = o4;
            }
        }
    }
}

__global__ __launch_bounds__(512) void mgemm_kernel(
    const unsigned short* __restrict__ A,
    const unsigned short* __restrict__ W, int ldw,
    const float* __restrict__ bias,
    const float* __restrict__ pos,
    const float* __restrict__ res,
    float* __restrict__ outf,
    unsigned short* __restrict__ outb,
    unsigned short* __restrict__ outbt,
    int act)
{
    gemm_body<16>(A, nullptr, W, ldw, bias, pos, res, outf, outb, outbt, act,
                  blockIdx.x);
}

// Q/K/V fused: blockIdx.y selects job (0=Q, 1=K, 2=V^T)
__global__ __launch_bounds__(512) void qkv_kernel(
    const unsigned short* __restrict__ qinb, const unsigned short* __restrict__ curb,
    const unsigned short* __restrict__ Wq, const unsigned short* __restrict__ Wk,
    const unsigned short* __restrict__ Wv,
    const float* __restrict__ qb, const float* __restrict__ kb,
    const float* __restrict__ vb,
    const float* __restrict__ posK, const float* __restrict__ posV,
    unsigned short* __restrict__ QBb, unsigned short* __restrict__ KBb,
    unsigned short* __restrict__ VTb)
{
    const int job = blockIdx.y;
    const unsigned short* A = (job == 0) ? qinb : curb;
    const unsigned short* W = (job == 0) ? Wq : (job == 1) ? Wk : Wv;
    const float* bias = (job == 0) ? qb : (job == 1) ? kb : vb;
    const float* pos  = (job == 0) ? nullptr : (job == 1) ? posK : posV;
    unsigned short* outb  = (job == 0) ? QBb : (job == 1) ? KBb : nullptr;
    unsigned short* outbt = (job == 2) ? VTb : nullptr;
    gemm_body<16>(A, nullptr, W, 512, bias, pos, nullptr, nullptr, outb, outbt, 0,
                  blockIdx.x);
}

// Decoder fused: dec = [log_feats | x_t] @ decw^T + decb  (K=1024, two A sources)
__global__ __launch_bounds__(512) void dec_kernel(
    const unsigned short* __restrict__ R0b, const unsigned short* __restrict__ R1b,
    const unsigned short* __restrict__ Wd, const float* __restrict__ decb,
    float* __restrict__ dec)
{
    gemm_body<32>(R0b, R1b, Wd, 1024, decb, nullptr, nullptr, dec, nullptr, nullptr,
                  0, blockIdx.x);
}

// ---------------------------------------------------------------------------
// Split-K small-M GEMM for the temb path.
// ---------------------------------------------------------------------------
__global__ __launch_bounds__(256) void skgemm_kernel(
    const float* __restrict__ A, int K,
    const float* __restrict__ W, int N,
    float* __restrict__ P)
{
    __shared__ float As[32][128];
    const int tid = threadIdx.x;
    const int kz  = blockIdx.y;
    const int c   = blockIdx.x * 256 + tid;

    #pragma unroll
    for (int i = 0; i < 16; ++i) {
        const int idx = i * 256 + tid;
        const int r = idx >> 7, k = idx & 127;
        As[r][k] = A[(size_t)r * K + kz * 128 + k];
    }
    __syncthreads();

    float acc[32];
    #pragma unroll
    for (int r = 0; r < 32; ++r) acc[r] = 0.f;

    const float* wrow = W + (size_t)c * K + kz * 128;
    for (int k4 = 0; k4 < 32; ++k4) {
        const float4 w = reinterpret_cast<const float4*>(wrow)[k4];
        #pragma unroll
        for (int r = 0; r < 32; ++r) {
            const float4 a = *reinterpret_cast<const float4*>(&As[r][k4 * 4]);
            acc[r] = fmaf(w.x, a.x, fmaf(w.y, a.y, fmaf(w.z, a.z, fmaf(w.w, a.w, acc[r]))));
        }
    }

    float* pp = P + ((size_t)kz * N + c) * 32;
    #pragma unroll
    for (int r = 0; r < 32; ++r) pp[r] = acc[r];
}

__global__ __launch_bounds__(256) void skreduce_kernel(
    const float* __restrict__ P, int KS, const float* __restrict__ bias,
    float* __restrict__ out, int N, int act)
{
    const int idx = blockIdx.x * 256 + threadIdx.x;
    const int r = idx & 31, c = idx >> 5;
    float s = 0.f;
    for (int kz = 0; kz < KS; ++kz)
        s += P[(size_t)kz * N * 32 + idx];
    s += bias[c];
    if (act == 2) s = s / (1.f + __expf(-s));
    out[(size_t)r * N + c] = s;
}

// ---------------------------------------------------------------------------
// MFMA causal flash attention (round-8 version, unchanged).
// ---------------------------------------------------------------------------
__global__ __launch_bounds__(256) void mattn_kernel(
    const unsigned short* __restrict__ Q, const unsigned short* __restrict__ K,
    const unsigned short* __restrict__ VT, const unsigned short* __restrict__ Qin,
    float* __restrict__ Sout)
{
    __shared__ alignas(16) unsigned short kT[2][4096];
    __shared__ alignas(16) unsigned short vT[2][4096];
    __shared__ unsigned short pl[4][1024];

    const int qt = blockIdx.x;
    const int h  = blockIdx.y;
    const int b  = blockIdx.z;
    const int tid = threadIdx.x, lane = tid & 63, wid = tid >> 6;
    const int fr = lane & 15, fq = lane >> 4;
    const int hc = h * HDD;

    const int c0i = tid, c1i = 256 + tid;
    const int r0s = c0i >> 3, j0s = c0i & 7, d0s = ((j0s ^ (r0s & 7)) << 3);
    const int r1s = c1i >> 3, j1s = c1i & 7, d1s = ((j1s ^ (r1s & 7)) << 3);
    const unsigned short* kS0 = K + (size_t)b * LL * CHN + (size_t)r0s * CHN + hc + d0s;
    const unsigned short* kS1 = K + (size_t)b * LL * CHN + (size_t)r1s * CHN + hc + d1s;
    const unsigned short* vS0 = VT + ((size_t)(b * NHH + h) * 64 + r0s) * 512 + d0s;
    const unsigned short* vS1 = VT + ((size_t)(b * NHH + h) * 64 + r1s) * 512 + d1s;

    #define AT_STAGE(buf, ch)                                              \
        do {                                                               \
            const int o = (ch) * 64;                                       \
            gl16(kS0 + (size_t)o * CHN, &kT[buf][wid * 512]);              \
            gl16(kS1 + (size_t)o * CHN, &kT[buf][2048 + wid * 512]);       \
            gl16(vS0 + o, &vT[buf][wid * 512]);                            \
            gl16(vS1 + o, &vT[buf][2048 + wid * 512]);                     \
        } while (0)

    const size_t qrow = (size_t)b * LL + qt * 64 + wid * 16 + fr;
    short8 qf[2];
    qf[0] = *reinterpret_cast<const short8*>(Q + qrow * CHN + hc + fq * 8);
    qf[1] = *reinterpret_cast<const short8*>(Q + qrow * CHN + hc + 32 + fq * 8);

    f32x4 oacc[4];
    #pragma unroll
    for (int n = 0; n < 4; ++n) oacc[n] = (f32x4){0.f, 0.f, 0.f, 0.f};
    float mrow[4], lrow[4];
    #pragma unroll
    for (int r = 0; r < 4; ++r) { mrow[r] = -1e30f; lrow[r] = 0.f; }

    AT_STAGE(0, 0);
    __syncthreads();

    for (int ch = 0; ch <= qt; ++ch) {
        const int cur = ch & 1;
        if (ch < qt) AT_STAGE(cur ^ 1, ch + 1);

        f32x4 sacc[4];
        #pragma unroll
        for (int n = 0; n < 4; ++n) sacc[n] = (f32x4){0.f, 0.f, 0.f, 0.f};
        __builtin_amdgcn_s_setprio(1);
        #pragma unroll
        for (int kk = 0; kk < 2; ++kk) {
            #pragma unroll
            for (int n = 0; n < 4; ++n) {
                const short8 kf = *reinterpret_cast<const short8*>(
                    &kT[cur][SWZ(n * 16 + fr, kk * 32 + fq * 8)]);
                sacc[n] = __builtin_amdgcn_mfma_f32_16x16x32_bf16(qf[kk], kf, sacc[n], 0, 0, 0);
            }
        }
        __builtin_amdgcn_s_setprio(0);

        const bool diag = (ch == qt);
        #pragma unroll
        for (int r = 0; r < 4; ++r) {
            float sv[4];
            #pragma unroll
            for (int n = 0; n < 4; ++n) {
                float v = sacc[n][r] * 0.125f;
                if (diag && (n * 16 + fr > wid * 16 + fq * 4 + r)) v = -1e30f;
                sv[n] = v;
            }
            float cm = fmaxf(fmaxf(sv[0], sv[1]), fmaxf(sv[2], sv[3]));
            cm = fmaxf(cm, __shfl_xor(cm, 1));
            cm = fmaxf(cm, __shfl_xor(cm, 2));
            cm = fmaxf(cm, __shfl_xor(cm, 4));
            cm = fmaxf(cm, __shfl_xor(cm, 8));
            const float mn = fmaxf(mrow[r], cm);
            const float f = __expf(mrow[r] - mn);
            mrow[r] = mn;
            float ps = 0.f;
            #pragma unroll
            for (int n = 0; n < 4; ++n) { sv[n] = __expf(sv[n] - mn); ps += sv[n]; }
            ps += __shfl_xor(ps, 1);
            ps += __shfl_xor(ps, 2);
            ps += __shfl_xor(ps, 4);
            ps += __shfl_xor(ps, 8);
            lrow[r] = lrow[r] * f + ps;
            #pragma unroll
            for (int n = 0; n < 4; ++n) {
                oacc[n][r] *= f;
                pl[wid][SWZ(fq * 4 + r, n * 16 + fr)] = f2b(sv[n]);
            }
        }

        __builtin_amdgcn_s_setprio(1);
        #pragma unroll
        for (int kk = 0; kk < 2; ++kk) {
            const short8 pa = *reinterpret_cast<const short8*>(
                &pl[wid][SWZ(fr, kk * 32 + fq * 8)]);
            #pragma unroll
            for (int n = 0; n < 4; ++n) {
                const short8 vf = *reinterpret_cast<const short8*>(
                    &vT[cur][SWZ(n * 16 + fr, kk * 32 + fq * 8)]);
                oacc[n] = __builtin_amdgcn_mfma_f32_16x16x32_bf16(pa, vf, oacc[n], 0, 0, 0);
            }
        }
        __builtin_amdgcn_s_setprio(0);
        __syncthreads();
    }
    #undef AT_STAGE

    const size_t orow0 = (size_t)b * LL + qt * 64 + wid * 16 + fq * 4;
    #pragma unroll
    for (int r = 0; r < 4; ++r) {
        const float inv = 1.f / lrow[r];
        const size_t rowidx = (orow0 + r) * CHN + hc;
        #pragma unroll
        for (int n = 0; n < 4; ++n) {
            const int d = n * 16 + fr;
            Sout[rowidx + d] = oacc[n][r] * inv + b2f(Qin[rowidx + d]);
        }
    }
}

// ---------------------------------------------------------------------------
__global__ __launch_bounds__(256) void temb_embed_kernel(
    const int* __restrict__ t, float* __restrict__ T0)
{
    const int idx = blockIdx.x * 256 + threadIdx.x;
    const int b = idx >> 9, j = idx & 511;
    const float tv = (float)t[b];
    const int jj = (j < 256) ? j : j - 256;
    const float freq = __expf((float)jj * (-9.210340371976184f / 255.f));
    const float ang = tv * freq;
    T0[idx] = (j < 256) ? sinf(ang) : cosf(ang);
}

__global__ __launch_bounds__(256) void add_temb_kernel(
    const float* __restrict__ xin, const float* __restrict__ temb,
    unsigned short* __restrict__ out)
{
    const size_t i4 = (size_t)blockIdx.x * 256 + threadIdx.x;
    const size_t elem = i4 * 4;
    const int b = (int)(elem >> 18);
    const int c = (int)(elem & (CHN - 1));
    const float4 a = reinterpret_cast<const float4*>(xin)[i4];
    const float4 tv = *reinterpret_cast<const float4*>(temb + (size_t)b * CHN + c);
    ushort4 o;
    o.x = f2b(a.x + tv.x); o.y = f2b(a.y + tv.y);
    o.z = f2b(a.z + tv.z); o.w = f2b(a.w + tv.w);
    reinterpret_cast<ushort4*>(out)[i4] = o;
}

// ---------------------------------------------------------------------------
extern "C" void kernel_launch(void* const* d_in, const int* in_sizes, int n_in,
                              void* d_out, int out_size, void* d_ws, size_t ws_size,
                              hipStream_t stream)
{
    (void)in_sizes; (void)n_in; (void)out_size; (void)ws_size;
    const float* log_seqs = (const float*)d_in[0];
    const float* seqs_nxt = (const float*)d_in[1];
    const int*   tt       = (const int*)d_in[2];
    const float* qw  = (const float*)d_in[3];
    const float* qb  = (const float*)d_in[4];
    const float* kw  = (const float*)d_in[5];
    const float* kb  = (const float*)d_in[6];
    const float* vw  = (const float*)d_in[7];
    const float* vb  = (const float*)d_in[8];
    const float* ln1g = (const float*)d_in[9];
    const float* ln1b = (const float*)d_in[10];
    const float* ln2g = (const float*)d_in[11];
    const float* ln2b = (const float*)d_in[12];
    const float* c1w = (const float*)d_in[13];
    const float* c1b = (const float*)d_in[14];
    const float* c2w = (const float*)d_in[15];
    const float* c2b = (const float*)d_in[16];
    const float* posK = (const float*)d_in[17];
    const float* posV = (const float*)d_in[18];
    const float* lng = (const float*)d_in[19];
    const float* lnb = (const float*)d_in[20];
    const float* tw0 = (const float*)d_in[21];
    const float* tb0 = (const float*)d_in[22];
    const float* tw1 = (const float*)d_in[23];
    const float* tb1 = (const float*)d_in[24];
    const float* tw2 = (const float*)d_in[25];
    const float* tb2 = (const float*)d_in[26];
    const float* decw = (const float*)d_in[27];
    const float* decb = (const float*)d_in[28];

    const size_t SZ = (size_t)BB * LL * CHN;  // 8388608
    const int M = BB * LL;                    // 16384
    float* out = (float*)d_out;
    float* log_feats = out;
    float* dec = out + SZ;
    unsigned short* QBb = (unsigned short*)dec;        // Q bf16 until decoder
    unsigned short* VTb = (unsigned short*)log_feats;  // V^T bf16 until final LN

    float* ws = (float*)d_ws;
    float* S = ws;                                            // SZ f32
    unsigned short* KBb = (unsigned short*)(ws + SZ);         // SZ bf16
    unsigned short* R0  = (unsigned short*)(ws + SZ + SZ / 2);
    unsigned short* R1  = (unsigned short*)(ws + 2 * SZ);
    unsigned short* WBu = (unsigned short*)(ws + 2 * SZ + SZ / 2);  // 3145728 bf16
    float* T0 = ws + 2 * SZ + SZ / 2 + 1572864;
    float* T1 = T0 + 32 * CHN;
    float* T2 = T1 + 32 * 2048;
    float* T3 = T2 + 32 * 2048;
    float* P  = S;   // split-K partials (S is dead after the final LN)

    const size_t WQ = 0, WK = 524288, WV = 1048576, WC1 = 1572864,
                 WC2 = 2097152, WDEC = 2621440;

    auto mg = [&](const unsigned short* A, const unsigned short* W, int ldw,
                  const float* bias, const float* pos, const float* res,
                  float* outf, unsigned short* outb, unsigned short* outbt, int act) {
        mgemm_kernel<<<256, 512, 0, stream>>>(A, W, ldw, bias, pos, res,
                                              outf, outb, outbt, act);
    };
    auto skg = [&](const float* A, int K, const float* W, int N,
                   const float* bias, float* o, int act) {
        skgemm_kernel<<<dim3(N / 256, K / 128), 256, 0, stream>>>(A, K, W, N, P);
        skreduce_kernel<<<(N * 32) / 256, 256, 0, stream>>>(P, K / 128, bias, o, N, act);
    };

    // weight + input conversions (one fat launch + one big cvt)
    cvt6_kernel<<<dim3(512, 6), 256, 0, stream>>>(qw, kw, vw, c1w, c2w, decw, WBu);
    cvt_kernel<<<(int)(SZ / 4 / 256), 256, 0, stream>>>(log_seqs, R1, (int)(SZ / 4));

    const float* cur = log_seqs;
    for (int i = 0; i < 2; ++i) {
        const size_t wo = (size_t)i * 262144;
        const size_t bo = (size_t)i * CHN;
        unsigned short* qinb = (i == 0) ? R0 : R1;
        unsigned short* curb = (i == 0) ? R1 : R0;
        unsigned short* smb  = qinb;
        unsigned short* hb   = curb;
        unsigned short* ncb  = (i == 0) ? qinb : nullptr;

        ln_kernel<<<M, 256, 0, stream>>>(cur, ln1g + bo, ln1b + bo, nullptr, qinb);
        qkv_kernel<<<dim3(256, 3), 512, 0, stream>>>(
            qinb, curb, WBu + WQ + wo, WBu + WK + wo, WBu + WV + wo,
            qb + bo, kb + bo, vb + bo, posK, posV, QBb, KBb, VTb);
        mattn_kernel<<<dim3(LL / 64, NHH, BB), 256, 0, stream>>>(QBb, KBb, VTb, qinb, S);
        ln_kernel<<<M, 256, 0, stream>>>(S, ln2g + bo, ln2b + bo, S, smb);
        mg(smb, WBu + WC1 + wo, 512, c1b + bo, nullptr, nullptr, nullptr, hb, nullptr, 1);
        mg(hb, WBu + WC2 + wo, 512, c2b + bo, nullptr, S, S, ncb, nullptr, 0);
        cur = S;
    }

    ln_kernel<<<M, 256, 0, stream>>>(S, lng, lnb, log_feats, R0);

    temb_embed_kernel<<<(BB * CHN) / 256, 256, 0, stream>>>(tt, T0);
    skg(T0, 512, tw0, 2048, tb0, T1, 2);
    skg(T1, 2048, tw1, 2048, tb1, T2, 2);
    skg(T2, 2048, tw2, 512, tb2, T3, 0);
    add_temb_kernel<<<(M * CHN / 4) / 256, 256, 0, stream>>>(seqs_nxt, T3, R1);

    dec_kernel<<<256, 512, 0, stream>>>(R0, R1, WBu + WDEC, decb, dec);
}